// Round 9
// baseline (318.787 us; speedup 1.0000x reference)
//
#include <hip/hip_runtime.h>
#include <hip/hip_bf16.h>

#define N_NODES 50000
#define N_EDGES 800000
#define NF      64
#define NG      50
#define NPG     (N_NODES / NG)   // 1000 nodes per graph
#define SCAN_NBLK ((N_NODES + 255) / 256)   // 196
#define MCHUNK  20               // blocks per graph for means
#define MROWS   (NPG / MCHUNK)   // 50 nodes per means block
#define NTILES  (N_NODES / 16)   // 3125 exact
#define GATHER_BLKS ((NTILES + 3) / 4)      // 782: one tile per wave
#define FP_CHUNKS 896
#define FP_CHSZ  ((N_EDGES + FP_CHUNKS - 1) / FP_CHUNKS)   // 893
#define FP_NPP   (N_NODES / 8)   // 6250 nodes per partition
#define DEG_BLKS (FP_CHUNKS * 8) // 7168
#define INIT_BLKS ((N_NODES * 32 + 255) / 256)  // 6250
#define DEGS 5                   // deg stride shift: 32 ints = 128B per counter

typedef __attribute__((ext_vector_type(8))) short bf16x8;
typedef __attribute__((ext_vector_type(4))) float f32x4;
typedef unsigned short u16;
typedef unsigned char u8;

// round-half-up fp32->bf16 pair pack (inputs are finite)
__device__ inline unsigned pkbf(float a, float b) {
    unsigned ua = __float_as_uint(a) + 0x8000u;
    unsigned ub = __float_as_uint(b) + 0x8000u;
    return (ua >> 16) | (ub & 0xFFFF0000u);
}
__device__ inline short bf1(float a) {
    return (short)((__float_as_uint(a) + 0x8000u) >> 16);
}
__device__ inline float lo2f(unsigned u) { return __uint_as_float(u << 16); }
__device__ inline float hi2f(unsigned u) { return __uint_as_float(u & 0xFFFF0000u); }
// packed accumulate: float2 adds -> v_pk_add_f32
__device__ inline void accp(float2* a, uint4 v) {
    a[0].x += lo2f(v.x); a[0].y += hi2f(v.x);
    a[1].x += lo2f(v.y); a[1].y += hi2f(v.y);
    a[2].x += lo2f(v.z); a[2].y += hi2f(v.z);
    a[3].x += lo2f(v.w); a[3].y += hi2f(v.w);
}

// ---------------------------------------------------------------------------
// FUSED: degree histogram (blocks [0,DEG_BLKS)) + node init embeddings.
// R19: histogram atomicAdd RETURNS the edge's CSR slot (epos) -> k_fill is
// atomic-free. R22 NOTE: 800K atomics / 44us = ~7.6 RMW/cy chip-wide — this
// is a device-atomic THROUGHPUT ceiling (padding only bought 3us). CSR build
// via atomics is pinned at ~40us; only a full sort-based build beats it.
__global__ void k_deg_init(const int* __restrict__ col, int* __restrict__ deg,
                           u8* __restrict__ epos,
                           const float* __restrict__ x, const float* __restrict__ Wi,
                           const float* __restrict__ We1,
                           u16* __restrict__ cur, u16* __restrict__ h) {
    if (blockIdx.x < DEG_BLKS) {
        int part = blockIdx.x & 7, chunk = blockIdx.x >> 3;
        int lo = part * FP_NPP, hi = lo + FP_NPP;
        int e0 = chunk * FP_CHSZ;
        int e1 = min(N_EDGES, e0 + FP_CHSZ);
        for (int e = e0 + threadIdx.x; e < e1; e += 256) {
            int c = col[e];
            if (c >= lo && c < hi) {
                int pos = atomicAdd(&deg[c << DEGS], 1);
                epos[e] = (u8)pos;
            }
        }
        return;
    }
    int idx = (blockIdx.x - DEG_BLKS) * 256 + threadIdx.x;   // N*32
    int node = idx >> 5, q = idx & 31;
    if (node >= N_NODES) return;
    int f0 = 2 * q, f1 = 2 * q + 1;
    float4 xv = ((const float4*)x)[node];
    float c0 = xv.x * Wi[f0] + xv.y * Wi[64 + f0] + xv.z * Wi[128 + f0] + xv.w * Wi[192 + f0];
    float c1 = xv.x * Wi[f1] + xv.y * Wi[64 + f1] + xv.z * Wi[128 + f1] + xv.w * Wi[192 + f1];
    ((unsigned*)cur)[node * 32 + q] = pkbf(fmaxf(c0, 0.f), fmaxf(c1, 0.f));
    float h0 = xv.x * We1[f0] + xv.y * We1[63 + f0] + xv.z * We1[126 + f0] + xv.w * We1[189 + f0];
    h0 = fmaxf(h0, 0.f);
    float h1 = 0.f;
    if (f1 < 63) {
        h1 = xv.x * We1[f1] + xv.y * We1[63 + f1] + xv.z * We1[126 + f1] + xv.w * We1[189 + f1];
        h1 = fmaxf(h1, 0.f);
    }
    ((unsigned*)h)[node * 32 + q] = pkbf(h0, h1);
}

// ---------------------------------------------------------------------------
// Spin-free scan (R16: never spin across blocks) + degree histogram for the
// counting sort (R17: degree-adjacent tiles; small but positive).
__global__ void k_blocksum(const int* __restrict__ deg, int* __restrict__ partials,
                           int* __restrict__ dmax, int* __restrict__ hist) {
    __shared__ int lh[256];
    int t = threadIdx.x;
    lh[t] = 0;
    __syncthreads();
    int i = blockIdx.x * 256 + t;
    int d = (i < N_NODES) ? deg[i << DEGS] : 0;
    if (i < N_NODES) atomicAdd(&lh[min(d, 255)], 1);
    int v = d, m = d;
    for (int off = 32; off; off >>= 1) {
        v += __shfl_xor(v, off, 64);
        m = max(m, __shfl_xor(m, off, 64));
    }
    __shared__ int s[4];
    if ((t & 63) == 0) { s[t >> 6] = v; atomicMax(dmax, m); }
    __syncthreads();
    if (t == 0) partials[blockIdx.x] = s[0] + s[1] + s[2] + s[3];
    if (lh[t]) atomicAdd(&hist[t], lh[t]);
}

// Exclusive scan over deg -> rowptr, plus two-level counting-sort scatter
// (R18: LDS ranks + one global atomic per non-empty bin per block).
__global__ __launch_bounds__(256) void k_scanfinal2(
        const int* __restrict__ deg, const int* __restrict__ partials,
        const int* __restrict__ hist, int* __restrict__ rowptr,
        int* __restrict__ binBump, int* __restrict__ perm) {
    int b = blockIdx.x, t = threadIdx.x;
    __shared__ int lh[256], lbase[256];
    lh[t] = 0;
    // prev = sum of partials[0..b)
    int p = (t < b) ? partials[t] : 0;     // b <= 195 < 256
    for (int off = 32; off; off >>= 1) p += __shfl_xor(p, off, 64);
    __shared__ int sr[4];
    if ((t & 63) == 0) sr[t >> 6] = p;
    __syncthreads();                        // sr ready + lh zeroed
    int prev = sr[0] + sr[1] + sr[2] + sr[3];
    int i = b * 256 + t;
    int v = (i < N_NODES) ? deg[i << DEGS] : 0;
    int bin = min(v, 255);
    int rank = 0;
    if (i < N_NODES) rank = atomicAdd(&lh[bin], 1);   // LDS atomic: local rank
    __shared__ int s[256];
    // scan 1: exclusive prefix of hist (bin bases)
    int hv = hist[t];
    s[t] = hv;
    __syncthreads();
    for (int off = 1; off < 256; off <<= 1) {
        int u = (t >= off) ? s[t - off] : 0;
        __syncthreads();
        s[t] += u;
        __syncthreads();
    }
    int hpref = s[t] - hv;   // exclusive prefix for bin t
    // scan 2: local exclusive scan of deg
    __syncthreads();
    s[t] = v;
    __syncthreads();
    for (int off = 1; off < 256; off <<= 1) {
        int u = (t >= off) ? s[t - off] : 0;
        __syncthreads();
        s[t] += u;
        __syncthreads();
    }
    int ex = prev + s[t] - v;
    if (i < N_NODES) rowptr[i] = ex;
    if (b == 0 && t == 0) rowptr[N_NODES] = N_EDGES;
    // one global atomic per non-empty bin -> block base in that bin
    __syncthreads();
    if (lh[t] > 0) lbase[t] = hpref + atomicAdd(&binBump[t], lh[t]);
    __syncthreads();
    if (i < N_NODES) perm[lbase[bin] + rank] = i;
}

// CSR fill: ATOMIC-FREE streaming (R19) — slot comes from epos computed in
// the deg pass. Destination-partitioned so csr writes stay XCD-local.
__global__ void k_fill(const int* __restrict__ row, const int* __restrict__ col,
                       const int* __restrict__ rowptr, const u8* __restrict__ epos,
                       u16* __restrict__ csr) {
    int part = blockIdx.x & 7, chunk = blockIdx.x >> 3;
    int lo = part * FP_NPP, hi = lo + FP_NPP;
    int e0 = chunk * FP_CHSZ;
    int e1 = min(N_EDGES, e0 + FP_CHSZ);
    for (int e = e0 + threadIdx.x; e < e1; e += 256) {
        int c = col[e];
        if (c >= lo && c < hi)
            csr[rowptr[c] + epos[e]] = (u16)row[e];
    }
}

// ---------------------------------------------------------------------------
// R22: LEAN standalone gather (de-fused from the MFMA layers). The fused
// kernels carried 32KB weight-LDS + MFMA frags in one allocation -> ~200
// VGPR -> 2 blocks/CU (26% occupancy) while the 1-tile-per-wave decomposition
// allows 3 (12 waves/CU). Gather is latency x concurrency bound: resident
// waves are the lever. This kernel has NO LDS and ~80 VGPR; writes agg bf16
// [N][64] node-major (the layer kernels read rows like they read ee/cur —
// identical fragment math, bitwise-identical numerics).
// 4-edge pipeline, 8 uint4 in flight (R15: do not deepen).
__global__ __launch_bounds__(256) void k_gather(
        const u16* __restrict__ src, const int* __restrict__ rowptr,
        const u16* __restrict__ csr, const int* __restrict__ perm,
        u16* __restrict__ agg) {
    int t = threadIdx.x, wv = t >> 6, lane = t & 63;
    int m = lane & 15, q = lane >> 4;
    for (int tb = blockIdx.x * 4 + wv; tb < NTILES; tb += gridDim.x * 4) {
        int pn = perm[tb * 16 + m];
        int beg = rowptr[pn], end = rowptr[pn + 1];
        float2 ac[8];
#pragma unroll
        for (int i = 0; i < 8; i++) ac[i] = make_float2(0.f, 0.f);
        int j = beg;
        for (; j + 3 < end; j += 4) {
            int r0 = csr[j], r1 = csr[j + 1], r2 = csr[j + 2], r3 = csr[j + 3];
            const uint4* p0 = (const uint4*)(src + (size_t)r0 * 64 + q * 16);
            const uint4* p1 = (const uint4*)(src + (size_t)r1 * 64 + q * 16);
            const uint4* p2 = (const uint4*)(src + (size_t)r2 * 64 + q * 16);
            const uint4* p3 = (const uint4*)(src + (size_t)r3 * 64 + q * 16);
            uint4 v00 = p0[0], v01 = p0[1];
            uint4 v10 = p1[0], v11 = p1[1];
            uint4 v20 = p2[0], v21 = p2[1];
            uint4 v30 = p3[0], v31 = p3[1];
            accp(ac, v00); accp(ac + 4, v01);
            accp(ac, v10); accp(ac + 4, v11);
            accp(ac, v20); accp(ac + 4, v21);
            accp(ac, v30); accp(ac + 4, v31);
        }
        for (; j < end; j++) {
            int r = csr[j];
            const uint4* p = (const uint4*)(src + (size_t)r * 64 + q * 16);
            uint4 v0 = p[0], v1 = p[1];
            accp(ac, v0); accp(ac + 4, v1);
        }
        float inv = 1.0f / (float)(end - beg);   // deg > 0 always
        uint4 lo, hi;
        lo.x = pkbf(ac[0].x * inv, ac[0].y * inv);
        lo.y = pkbf(ac[1].x * inv, ac[1].y * inv);
        lo.z = pkbf(ac[2].x * inv, ac[2].y * inv);
        lo.w = pkbf(ac[3].x * inv, ac[3].y * inv);
        hi.x = pkbf(ac[4].x * inv, ac[4].y * inv);
        hi.y = pkbf(ac[5].x * inv, ac[5].y * inv);
        hi.z = pkbf(ac[6].x * inv, ac[6].y * inv);
        hi.w = pkbf(ac[7].x * inv, ac[7].y * inv);
        u16* arow = agg + (size_t)pn * 64 + q * 16;
        *(uint4*)arow       = lo;
        *(uint4*)(arow + 8) = hi;
    }
}

// edge embedding MFMA: A = [agg(h) cols 0..62 | deg/dmax col 63], B = We2.
// A rows read straight from global agg (coalesced 16B fragments).
__global__ __launch_bounds__(256) void k_edge2(
        const u16* __restrict__ agg, const int* __restrict__ rowptr,
        const int* __restrict__ dmax, const float* __restrict__ We2,
        const int* __restrict__ perm, u16* __restrict__ ee) {
    __shared__ unsigned SB[2][4][64][4];   // 8KB
    int t = threadIdx.x;
    for (int F = t; F < 512; F += 256) {
        int ks = F >> 8, tile = (F >> 6) & 3, ln = F & 63;
        int c = ln & 15, qq = ln >> 4;
        const float* W = We2 + (ks * 32 + qq * 8) * 64 + tile * 16 + c;
        unsigned d0 = pkbf(W[0],       W[64]);
        unsigned d1 = pkbf(W[2 * 64],  W[3 * 64]);
        unsigned d2 = pkbf(W[4 * 64],  W[5 * 64]);
        unsigned d3 = pkbf(W[6 * 64],  W[7 * 64]);
        int slot = ln ^ ((ln >> 3) & 7);
        SB[ks][tile][slot][0] = d0; SB[ks][tile][slot][1] = d1;
        SB[ks][tile][slot][2] = d2; SB[ks][tile][slot][3] = d3;
    }
    __syncthreads();
    int wv = t >> 6, lane = t & 63;
    int m = lane & 15, quad = lane >> 4;
    int slot = lane ^ ((lane >> 3) & 7);
    float idm = 1.0f / (float)dmax[0];
    for (int tb = blockIdx.x * 4 + wv; tb < NTILES; tb += gridDim.x * 4) {
        int base = tb * 16;
        int pn = perm[base + m];
        const u16* arow = agg + (size_t)pn * 64;
        float dv = (float)(rowptr[pn + 1] - rowptr[pn]) * idm;
        int prw[4];
#pragma unroll
        for (int r = 0; r < 4; r++) prw[r] = perm[base + quad * 4 + r];
        f32x4 acc[4];
#pragma unroll
        for (int i = 0; i < 4; i++) acc[i] = (f32x4){0.f, 0.f, 0.f, 0.f};
#pragma unroll
        for (int ks = 0; ks < 2; ks++) {
            bf16x8 a = *(const bf16x8*)(arow + ks * 32 + quad * 8);
            if (ks == 1 && quad == 3) a[7] = bf1(dv);   // k=63 column
#pragma unroll
            for (int tile = 0; tile < 4; tile++) {
                bf16x8 b = *(const bf16x8*)&SB[ks][tile][slot][0];
                acc[tile] = __builtin_amdgcn_mfma_f32_16x16x32_bf16(a, b, acc[tile], 0, 0, 0);
            }
        }
#pragma unroll
        for (int tile = 0; tile < 4; tile++)
#pragma unroll
            for (int r = 0; r < 4; r++)
                ee[(size_t)prw[r] * 64 + tile * 16 + m] =
                    (u16)bf1(fmaxf(acc[tile][r], 0.f));
    }
}

// MPNN layer MFMA (gather de-fused). A rows (agg/ee/cur) from global; XT LDS
// only for the msg tile (GEMM1 C-layout -> GEMM2 A-layout transpose).
template <bool F32OUT>
__global__ __launch_bounds__(256) void k_layer2(
        const u16* __restrict__ agg, const u16* __restrict__ ee,
        const u16* __restrict__ cur,
        const float* __restrict__ Wm, const float* __restrict__ Wu,
        const int* __restrict__ perm, void* __restrict__ outp) {
    __shared__ unsigned SB[2][4][4][64][4];   // 32KB
    __shared__ short XT[4][16][64];           // 8KB msg tile
    int t = threadIdx.x;
    for (int F = t; F < 2048; F += 256) {
        int g = F >> 10, ks = (F >> 8) & 3, tile = (F >> 6) & 3, ln = F & 63;
        int c = ln & 15, qq = ln >> 4;
        const float* W = (g ? Wu : Wm) + (ks * 32 + qq * 8) * 64 + tile * 16 + c;
        unsigned d0 = pkbf(W[0],      W[64]);
        unsigned d1 = pkbf(W[2 * 64], W[3 * 64]);
        unsigned d2 = pkbf(W[4 * 64], W[5 * 64]);
        unsigned d3 = pkbf(W[6 * 64], W[7 * 64]);
        int slot = ln ^ ((ln >> 3) & 7);
        SB[g][ks][tile][slot][0] = d0; SB[g][ks][tile][slot][1] = d1;
        SB[g][ks][tile][slot][2] = d2; SB[g][ks][tile][slot][3] = d3;
    }
    __syncthreads();
    int wv = t >> 6, lane = t & 63;
    int m = lane & 15, quad = lane >> 4;
    int slot = lane ^ ((lane >> 3) & 7);
    for (int tb = blockIdx.x * 4 + wv; tb < NTILES; tb += gridDim.x * 4) {
        int base = tb * 16;
        int pn = perm[base + m];
        const u16* arow = agg + (size_t)pn * 64;
        const u16* erow = ee  + (size_t)pn * 64;
        const u16* crow = cur + (size_t)pn * 64;
        int prw[4];
#pragma unroll
        for (int r = 0; r < 4; r++) prw[r] = perm[base + quad * 4 + r];
        f32x4 acc[4];
#pragma unroll
        for (int i = 0; i < 4; i++) acc[i] = (f32x4){0.f, 0.f, 0.f, 0.f};
        // GEMM1: k 0..63 = agg, 64..127 = ee (both global)
#pragma unroll
        for (int ks = 0; ks < 4; ks++) {
            bf16x8 a = (ks < 2)
                ? *(const bf16x8*)(arow + ks * 32 + quad * 8)
                : *(const bf16x8*)(erow + (ks - 2) * 32 + quad * 8);
#pragma unroll
            for (int tile = 0; tile < 4; tile++) {
                bf16x8 b = *(const bf16x8*)&SB[0][ks][tile][slot][0];
                acc[tile] = __builtin_amdgcn_mfma_f32_16x16x32_bf16(a, b, acc[tile], 0, 0, 0);
            }
        }
        // relu(msg) -> XT (wave-private) in A-readable swizzled layout
#pragma unroll
        for (int tile = 0; tile < 4; tile++)
#pragma unroll
            for (int r = 0; r < 4; r++) {
                int node = quad * 4 + r;
                int f = tile * 16 + m;
                int sidx = (((f >> 3) ^ (node & 7)) << 3) | (f & 7);
                XT[wv][node][sidx] = bf1(fmaxf(acc[tile][r], 0.f));
            }
        // GEMM2: k 0..63 = cur (global), 64..127 = msg (XT)
#pragma unroll
        for (int i = 0; i < 4; i++) acc[i] = (f32x4){0.f, 0.f, 0.f, 0.f};
#pragma unroll
        for (int ks = 0; ks < 4; ks++) {
            bf16x8 a;
            if (ks < 2) {
                a = *(const bf16x8*)(crow + ks * 32 + quad * 8);
            } else {
                int gp = ((ks - 2) * 4 + quad) ^ (m & 7);
                a = *(const bf16x8*)&XT[wv][m][gp << 3];
            }
#pragma unroll
            for (int tile = 0; tile < 4; tile++) {
                bf16x8 b = *(const bf16x8*)&SB[1][ks][tile][slot][0];
                acc[tile] = __builtin_amdgcn_mfma_f32_16x16x32_bf16(a, b, acc[tile], 0, 0, 0);
            }
        }
#pragma unroll
        for (int tile = 0; tile < 4; tile++)
#pragma unroll
            for (int r = 0; r < 4; r++) {
                float v = fmaxf(acc[tile][r], 0.f);
                size_t oi = (size_t)prw[r] * 64 + tile * 16 + m;
                if (F32OUT) ((float*)outp)[oi] = v;
                else        ((u16*)outp)[oi] = (u16)bf1(v);
            }
    }
}

// R21: atomic-free means partials (distinct addresses, no done-counter).
__global__ __launch_bounds__(256) void k_means2(const float* __restrict__ cur,
                                                float* __restrict__ pmeans) {
    int g = blockIdx.x / MCHUNK;
    int c = blockIdx.x % MCHUNK;
    int t = threadIdx.x, f = t & 63, q = t >> 6;
    int base = g * NPG + c * MROWS;
    float acc = 0.f;
    for (int n = base + q; n < base + MROWS; n += 4) acc += cur[(size_t)n * 64 + f];
    __shared__ float red[4][64];
    red[q][f] = acc;
    __syncthreads();
    if (q == 0)
        pmeans[(size_t)(g * MCHUNK + c) * 64 + f] =
            red[0][f] + red[1][f] + red[2][f] + red[3][f];
}

// r1[g] = sum_f relu((mean[g] @ Wp)[f]) * Wr[f]. One block.
__global__ __launch_bounds__(256) void k_pool2(
        const float* __restrict__ pmeans, const float* __restrict__ Wp,
        const float* __restrict__ Wr, float* __restrict__ r1) {
    __shared__ float sm[4][64];
    int wv = threadIdx.x >> 6, lane = threadIdx.x & 63;
    for (int g = wv; g < NG; g += 4) {
        float m = 0.f;
        const float* pm = pmeans + (size_t)g * MCHUNK * 64 + lane;
#pragma unroll
        for (int c = 0; c < MCHUNK; c++) m += pm[c * 64];
        sm[wv][lane] = m * (1.0f / NPG);
        float a2 = 0.f;
#pragma unroll 16
        for (int k = 0; k < 64; k++) a2 = fmaf(sm[wv][k], Wp[k * 64 + lane], a2);
        float v = fmaxf(a2, 0.f) * Wr[lane];
        for (int off = 32; off; off >>= 1) v += __shfl_xor(v, off, 64);
        if (lane == 0) r1[g] = v;
    }
}

// out[n] = b + r1[batch[n]] + dot(relu(cur[n]), Wr[64:])
__global__ void k_read2(const float* __restrict__ cur, const float* __restrict__ r1,
                        const int* __restrict__ batch, const float* __restrict__ Wr,
                        const float* __restrict__ br, float* __restrict__ out) {
    int idx = blockIdx.x * 256 + threadIdx.x;
    int node = idx >> 4;
    if (node >= N_NODES) return;
    int q = idx & 15;
    float4 c = *(const float4*)(cur + (size_t)node * 64 + q * 4);
    float4 w = *(const float4*)(Wr + 64 + q * 4);
    float v = fmaxf(c.x, 0.f) * w.x + fmaxf(c.y, 0.f) * w.y
            + fmaxf(c.z, 0.f) * w.z + fmaxf(c.w, 0.f) * w.w;
    v += __shfl_xor(v, 1, 64); v += __shfl_xor(v, 2, 64);
    v += __shfl_xor(v, 4, 64); v += __shfl_xor(v, 8, 64);
    if (q == 0) out[node] = v + r1[batch[node]] + br[0];
}

// ---------------------------------------------------------------------------
extern "C" void kernel_launch(void* const* d_in, const int* in_sizes, int n_in,
                              void* d_out, int out_size, void* d_ws, size_t ws_size,
                              hipStream_t stream) {
    const float* x    = (const float*)d_in[0];
    const float* Wi   = (const float*)d_in[1];
    const float* We1  = (const float*)d_in[2];
    const float* We2  = (const float*)d_in[3];
    const float* Wm   = (const float*)d_in[4];   // [3,128,64]
    const float* Wu   = (const float*)d_in[5];   // [3,128,64]
    const float* Wp   = (const float*)d_in[6];
    const float* Wr   = (const float*)d_in[7];
    const float* br   = (const float*)d_in[8];
    const int*   ei   = (const int*)d_in[9];     // [2,E]
    const int*   batch= (const int*)d_in[10];
    const int* row = ei;
    const int* col = ei + N_EDGES;
    float* out = (float*)d_out;

    char* w = (char*)d_ws;
    size_t off = 0;
    auto carve = [&](size_t bytes) -> void* {
        void* p = (void*)(w + off);
        off += (bytes + 255) & ~(size_t)255;
        return p;
    };
    // zero-init region (one memset: deg + dmax + hist + binBump)
    int*   deg      = (int*)carve((size_t)N_NODES * 4 * 32);   // 128B-strided counters
    int*   dmax     = (int*)carve(256);
    int*   hist     = (int*)carve(256 * 4);
    int*   binBump  = (int*)carve(256 * 4);
    size_t zero_span = off;
    int*   rowptr   = (int*)carve((size_t)(N_NODES + 1) * 4);
    u8*    epos     = (u8*)carve((size_t)N_EDGES);
    u16*   csr      = (u16*)carve((size_t)N_EDGES * 2);
    int*   partials = (int*)carve((size_t)SCAN_NBLK * 4);
    int*   perm     = (int*)carve((size_t)N_NODES * 4);
    float* pmeans   = (float*)carve((size_t)NG * MCHUNK * 64 * 4);
    u16*   agg      = (u16*)carve((size_t)N_NODES * 64 * 2);
    u16*   bufA     = (u16*)carve((size_t)N_NODES * 64 * 2);
    u16*   bufB     = (u16*)carve((size_t)N_NODES * 64 * 2);
    u16*   ee       = (u16*)carve((size_t)N_NODES * 64 * 2);
    float* curF     = (float*)carve((size_t)N_NODES * 64 * 4);
    float* r1       = (float*)carve((size_t)NG * 4);

    hipMemsetAsync(d_ws, 0, zero_span, stream);

    // CSR build fused with node init (epos = slot within node's segment)
    k_deg_init<<<DEG_BLKS + INIT_BLKS, 256, 0, stream>>>(col, deg, epos,
                                                         x, Wi, We1, bufA, bufB);
    // spin-free scan + counting-sort perm (bin prefix folded in)
    k_blocksum  <<<SCAN_NBLK, 256, 0, stream>>>(deg, partials, dmax, hist);
    k_scanfinal2<<<SCAN_NBLK, 256, 0, stream>>>(deg, partials, hist, rowptr,
                                                binBump, perm);
    // atomic-free streaming CSR fill
    k_fill      <<<DEG_BLKS, 256, 0, stream>>>(row, col, rowptr, epos, csr);

    // edge embedding: lean gather (bufB = h) then MFMA
    k_gather<<<GATHER_BLKS, 256, 0, stream>>>(bufB, rowptr, csr, perm, agg);
    k_edge2 <<<GATHER_BLKS, 256, 0, stream>>>(agg, rowptr, dmax, We2, perm, ee);

    // layer 1: A -> B
    k_gather<<<GATHER_BLKS, 256, 0, stream>>>(bufA, rowptr, csr, perm, agg);
    k_layer2<false><<<GATHER_BLKS, 256, 0, stream>>>(agg, ee, bufA, Wm, Wu, perm, bufB);
    // layer 2: B -> A
    k_gather<<<GATHER_BLKS, 256, 0, stream>>>(bufB, rowptr, csr, perm, agg);
    k_layer2<false><<<GATHER_BLKS, 256, 0, stream>>>(agg, ee, bufB,
                                                     Wm + 128 * 64, Wu + 128 * 64,
                                                     perm, bufA);
    // layer 3: A -> curF (fp32)
    k_gather<<<GATHER_BLKS, 256, 0, stream>>>(bufA, rowptr, csr, perm, agg);
    k_layer2<true> <<<GATHER_BLKS, 256, 0, stream>>>(agg, ee, bufA,
                                                     Wm + 2 * 128 * 64, Wu + 2 * 128 * 64,
                                                     perm, curF);

    // atomic-free means partials -> tiny pool kernel
    k_means2<<<NG * MCHUNK, 256, 0, stream>>>(curF, pmeans);
    k_pool2 <<<1, 256, 0, stream>>>(pmeans, Wp, Wr, r1);
    k_read2<<<(N_NODES * 16 + 255) / 256, 256, 0, stream>>>(curF, r1, batch, Wr, br, out);
}

// Round 10
// 310.937 us; speedup vs baseline: 1.0252x; 1.0252x over previous
//
#include <hip/hip_runtime.h>
#include <hip/hip_bf16.h>

#define N_NODES 50000
#define N_EDGES 800000
#define NF      64
#define NG      50
#define NPG     (N_NODES / NG)   // 1000 nodes per graph
#define SCAN_NBLK ((N_NODES + 255) / 256)   // 196
#define MCHUNK  20               // blocks per graph for means
#define MROWS   (NPG / MCHUNK)   // 50 nodes per means block
#define NTILES  (N_NODES / 16)   // 3125 exact
#define GATHER_BLKS ((NTILES + 3) / 4)      // 782: one tile per wave
#define FP_CHUNKS 896
#define FP_CHSZ  ((N_EDGES + FP_CHUNKS - 1) / FP_CHUNKS)   // 893
#define FP_NPP   (N_NODES / 8)   // 6250 nodes per partition
#define DEG_BLKS (FP_CHUNKS * 8) // 7168
#define INIT_BLKS ((N_NODES * 32 + 255) / 256)  // 6250
#define DEGS 5                   // deg stride shift: 32 ints = 128B per node

typedef __attribute__((ext_vector_type(8))) short bf16x8;
typedef __attribute__((ext_vector_type(4))) float f32x4;
typedef unsigned short u16;
typedef unsigned char u8;

// source-quarter of a row id (N/4 = 12500)
__device__ inline int src_qtr(int r) {
    return (r >= 12500) + (r >= 25000) + (r >= 37500);
}

// round-half-up fp32->bf16 pair pack (inputs are finite)
__device__ inline unsigned pkbf(float a, float b) {
    unsigned ua = __float_as_uint(a) + 0x8000u;
    unsigned ub = __float_as_uint(b) + 0x8000u;
    return (ua >> 16) | (ub & 0xFFFF0000u);
}
__device__ inline short bf1(float a) {
    return (short)((__float_as_uint(a) + 0x8000u) >> 16);
}
__device__ inline float lo2f(unsigned u) { return __uint_as_float(u << 16); }
__device__ inline float hi2f(unsigned u) { return __uint_as_float(u & 0xFFFF0000u); }
// packed accumulate: float2 adds -> v_pk_add_f32
__device__ inline void accp(float2* a, uint4 v) {
    a[0].x += lo2f(v.x); a[0].y += hi2f(v.x);
    a[1].x += lo2f(v.y); a[1].y += hi2f(v.y);
    a[2].x += lo2f(v.z); a[2].y += hi2f(v.z);
    a[3].x += lo2f(v.w); a[3].y += hi2f(v.w);
}

// ---------------------------------------------------------------------------
// FUSED: degree histogram (blocks [0,DEG_BLKS)) + node init embeddings.
// R19: histogram atomicAdd RETURNS the edge's CSR slot (epos) -> k_fill is
// atomic-free. R22: 800K atomics / 44us ~ device-atomic throughput ceiling —
// CSR-by-atomics is pinned at ~40us regardless of padding/partitioning.
// R23: FOUR sub-counters per node (one per source-quarter, same 128B line,
// same total atomic count) so the CSR lists come out source-quarter-sorted:
// the gather then reads a 1.6MB source window per phase -> L2-resident on
// every XCD (was: 70MB of 102MB missing L2 per gather pass).
__global__ void k_deg_init(const int* __restrict__ row, const int* __restrict__ col,
                           int* __restrict__ deg, u8* __restrict__ epos,
                           const float* __restrict__ x, const float* __restrict__ Wi,
                           const float* __restrict__ We1,
                           u16* __restrict__ cur, u16* __restrict__ h) {
    if (blockIdx.x < DEG_BLKS) {
        int part = blockIdx.x & 7, chunk = blockIdx.x >> 3;
        int lo = part * FP_NPP, hi = lo + FP_NPP;
        int e0 = chunk * FP_CHSZ;
        int e1 = min(N_EDGES, e0 + FP_CHSZ);
        for (int e = e0 + threadIdx.x; e < e1; e += 256) {
            int c = col[e];
            if (c >= lo && c < hi) {
                int qtr = src_qtr(row[e]);
                int pos = atomicAdd(&deg[(c << DEGS) + qtr * 8], 1);
                epos[e] = (u8)pos;
            }
        }
        return;
    }
    int idx = (blockIdx.x - DEG_BLKS) * 256 + threadIdx.x;   // N*32
    int node = idx >> 5, q = idx & 31;
    if (node >= N_NODES) return;
    int f0 = 2 * q, f1 = 2 * q + 1;
    float4 xv = ((const float4*)x)[node];
    float c0 = xv.x * Wi[f0] + xv.y * Wi[64 + f0] + xv.z * Wi[128 + f0] + xv.w * Wi[192 + f0];
    float c1 = xv.x * Wi[f1] + xv.y * Wi[64 + f1] + xv.z * Wi[128 + f1] + xv.w * Wi[192 + f1];
    ((unsigned*)cur)[node * 32 + q] = pkbf(fmaxf(c0, 0.f), fmaxf(c1, 0.f));
    float h0 = xv.x * We1[f0] + xv.y * We1[63 + f0] + xv.z * We1[126 + f0] + xv.w * We1[189 + f0];
    h0 = fmaxf(h0, 0.f);
    float h1 = 0.f;
    if (f1 < 63) {
        h1 = xv.x * We1[f1] + xv.y * We1[63 + f1] + xv.z * We1[126 + f1] + xv.w * We1[189 + f1];
        h1 = fmaxf(h1, 0.f);
    }
    ((unsigned*)h)[node * 32 + q] = pkbf(h0, h1);
}

// ---------------------------------------------------------------------------
// Spin-free scan (R16: never spin across blocks) + degree histogram for the
// counting sort (R17). Node degree = sum of the 4 quarter-counters.
__global__ void k_blocksum(const int* __restrict__ deg, int* __restrict__ partials,
                           int* __restrict__ dmax, int* __restrict__ hist) {
    __shared__ int lh[256];
    int t = threadIdx.x;
    lh[t] = 0;
    __syncthreads();
    int i = blockIdx.x * 256 + t;
    int d = 0;
    if (i < N_NODES) {
        const int* dp = deg + (i << DEGS);
        d = dp[0] + dp[8] + dp[16] + dp[24];
        atomicAdd(&lh[min(d, 255)], 1);
    }
    int v = d, m = d;
    for (int off = 32; off; off >>= 1) {
        v += __shfl_xor(v, off, 64);
        m = max(m, __shfl_xor(m, off, 64));
    }
    __shared__ int s[4];
    if ((t & 63) == 0) { s[t >> 6] = v; atomicMax(dmax, m); }
    __syncthreads();
    if (t == 0) partials[blockIdx.x] = s[0] + s[1] + s[2] + s[3];
    if (lh[t]) atomicAdd(&hist[t], lh[t]);
}

// Exclusive scan over deg -> rowptr, two-level counting-sort scatter (R18),
// and R23: pack per-node quarter offsets (0,d0,d0+d1,d0+d1+d2) into qoff u32
// (each offset < 256 since deg < 256).
__global__ __launch_bounds__(256) void k_scanfinal2(
        const int* __restrict__ deg, const int* __restrict__ partials,
        const int* __restrict__ hist, int* __restrict__ rowptr,
        unsigned* __restrict__ qoff,
        int* __restrict__ binBump, int* __restrict__ perm) {
    int b = blockIdx.x, t = threadIdx.x;
    __shared__ int lh[256], lbase[256];
    lh[t] = 0;
    // prev = sum of partials[0..b)
    int p = (t < b) ? partials[t] : 0;     // b <= 195 < 256
    for (int off = 32; off; off >>= 1) p += __shfl_xor(p, off, 64);
    __shared__ int sr[4];
    if ((t & 63) == 0) sr[t >> 6] = p;
    __syncthreads();                        // sr ready + lh zeroed
    int prev = sr[0] + sr[1] + sr[2] + sr[3];
    int i = b * 256 + t;
    int v = 0;
    if (i < N_NODES) {
        const int* dp = deg + (i << DEGS);
        int d0 = dp[0], d1 = dp[8], d2 = dp[16], d3 = dp[24];
        v = d0 + d1 + d2 + d3;
        qoff[i] = ((unsigned)d0 << 8) | ((unsigned)(d0 + d1) << 16)
                | ((unsigned)(d0 + d1 + d2) << 24);
    }
    int bin = min(v, 255);
    int rank = 0;
    if (i < N_NODES) rank = atomicAdd(&lh[bin], 1);   // LDS atomic: local rank
    __shared__ int s[256];
    // scan 1: exclusive prefix of hist (bin bases)
    int hv = hist[t];
    s[t] = hv;
    __syncthreads();
    for (int off = 1; off < 256; off <<= 1) {
        int u = (t >= off) ? s[t - off] : 0;
        __syncthreads();
        s[t] += u;
        __syncthreads();
    }
    int hpref = s[t] - hv;   // exclusive prefix for bin t
    // scan 2: local exclusive scan of deg
    __syncthreads();
    s[t] = v;
    __syncthreads();
    for (int off = 1; off < 256; off <<= 1) {
        int u = (t >= off) ? s[t - off] : 0;
        __syncthreads();
        s[t] += u;
        __syncthreads();
    }
    int ex = prev + s[t] - v;
    if (i < N_NODES) rowptr[i] = ex;
    if (b == 0 && t == 0) rowptr[N_NODES] = N_EDGES;
    // one global atomic per non-empty bin -> block base in that bin
    __syncthreads();
    if (lh[t] > 0) lbase[t] = hpref + atomicAdd(&binBump[t], lh[t]);
    __syncthreads();
    if (i < N_NODES) perm[lbase[bin] + rank] = i;
}

// CSR fill: ATOMIC-FREE streaming (R19); slot = rowptr + quarter offset +
// epos. Destination-partitioned so csr writes stay XCD-local.
__global__ void k_fill(const int* __restrict__ row, const int* __restrict__ col,
                       const int* __restrict__ rowptr, const unsigned* __restrict__ qoff,
                       const u8* __restrict__ epos, u16* __restrict__ csr) {
    int part = blockIdx.x & 7, chunk = blockIdx.x >> 3;
    int lo = part * FP_NPP, hi = lo + FP_NPP;
    int e0 = chunk * FP_CHSZ;
    int e1 = min(N_EDGES, e0 + FP_CHSZ);
    for (int e = e0 + threadIdx.x; e < e1; e += 256) {
        int c = col[e];
        if (c >= lo && c < hi) {
            int r = row[e];
            int qo = (qoff[c] >> (src_qtr(r) * 8)) & 255;
            csr[rowptr[c] + qo + epos[e]] = (u16)r;
        }
    }
}

// Per-wave fused gather (R8 fused structure — R9's de-fuse regressed 11us:
// agg round-trip + launches ate the occupancy gain). Edge lists are now
// source-quarter-sorted (R23), so this loop sweeps a 1.6MB source window at
// a time with no code change. 4-edge pipeline, 8 uint4 in flight (R15: do
// not deepen; R17: do not cap launch_bounds).
__device__ inline void gather_tile(const u16* __restrict__ src,
                                   const int* __restrict__ rowptr,
                                   const u16* __restrict__ csr,
                                   int node, int m, int q, int wv,
                                   short (*AT)[16][64]) {
    int beg = rowptr[node], end = rowptr[node + 1];
    float2 ac[8];
#pragma unroll
    for (int i = 0; i < 8; i++) ac[i] = make_float2(0.f, 0.f);
    int j = beg;
    for (; j + 3 < end; j += 4) {
        int r0 = csr[j], r1 = csr[j + 1], r2 = csr[j + 2], r3 = csr[j + 3];
        const uint4* p0 = (const uint4*)(src + (size_t)r0 * 64 + q * 16);
        const uint4* p1 = (const uint4*)(src + (size_t)r1 * 64 + q * 16);
        const uint4* p2 = (const uint4*)(src + (size_t)r2 * 64 + q * 16);
        const uint4* p3 = (const uint4*)(src + (size_t)r3 * 64 + q * 16);
        uint4 v00 = p0[0], v01 = p0[1];
        uint4 v10 = p1[0], v11 = p1[1];
        uint4 v20 = p2[0], v21 = p2[1];
        uint4 v30 = p3[0], v31 = p3[1];
        accp(ac, v00); accp(ac + 4, v01);
        accp(ac, v10); accp(ac + 4, v11);
        accp(ac, v20); accp(ac + 4, v21);
        accp(ac, v30); accp(ac + 4, v31);
    }
    for (; j < end; j++) {
        int r = csr[j];
        const uint4* p = (const uint4*)(src + (size_t)r * 64 + q * 16);
        uint4 v0 = p[0], v1 = p[1];
        accp(ac, v0); accp(ac + 4, v1);
    }
    float inv = 1.0f / (float)(end - beg);   // deg > 0 always
    uint4 lo, hi;
    lo.x = pkbf(ac[0].x * inv, ac[0].y * inv);
    lo.y = pkbf(ac[1].x * inv, ac[1].y * inv);
    lo.z = pkbf(ac[2].x * inv, ac[2].y * inv);
    lo.w = pkbf(ac[3].x * inv, ac[3].y * inv);
    hi.x = pkbf(ac[4].x * inv, ac[4].y * inv);
    hi.y = pkbf(ac[5].x * inv, ac[5].y * inv);
    hi.z = pkbf(ac[6].x * inv, ac[6].y * inv);
    hi.w = pkbf(ac[7].x * inv, ac[7].y * inv);
    *(uint4*)&AT[wv][m][((2 * q) ^ (m & 7)) * 8]     = lo;
    *(uint4*)&AT[wv][m][((2 * q + 1) ^ (m & 7)) * 8] = hi;
}

// fused h-gather + edge_emb MFMA, degree-sorted tiles via perm.
__global__ __launch_bounds__(256) void k_edge_f(
        const u16* __restrict__ h, const int* __restrict__ rowptr,
        const u16* __restrict__ csr, const int* __restrict__ dmax,
        const float* __restrict__ We2, const int* __restrict__ perm,
        u16* __restrict__ ee) {
    __shared__ unsigned SB[2][4][64][4];   // 8KB
    __shared__ short AT[4][16][64];        // 8KB
    int t = threadIdx.x;
    for (int F = t; F < 512; F += 256) {
        int ks = F >> 8, tile = (F >> 6) & 3, ln = F & 63;
        int c = ln & 15, qq = ln >> 4;
        const float* W = We2 + (ks * 32 + qq * 8) * 64 + tile * 16 + c;
        unsigned d0 = pkbf(W[0],       W[64]);
        unsigned d1 = pkbf(W[2 * 64],  W[3 * 64]);
        unsigned d2 = pkbf(W[4 * 64],  W[5 * 64]);
        unsigned d3 = pkbf(W[6 * 64],  W[7 * 64]);
        int slot = ln ^ ((ln >> 3) & 7);
        SB[ks][tile][slot][0] = d0; SB[ks][tile][slot][1] = d1;
        SB[ks][tile][slot][2] = d2; SB[ks][tile][slot][3] = d3;
    }
    __syncthreads();
    int wv = t >> 6, lane = t & 63;
    int m = lane & 15, quad = lane >> 4;
    int slot = lane ^ ((lane >> 3) & 7);
    float idm = 1.0f / (float)dmax[0];
    for (int tb = blockIdx.x * 4 + wv; tb < NTILES; tb += gridDim.x * 4) {
        int base = tb * 16;
        int pn = perm[base + m];
        gather_tile(h, rowptr, csr, pn, m, quad, wv, AT);
        float dv = (float)(rowptr[pn + 1] - rowptr[pn]) * idm;
        int prw[4];
#pragma unroll
        for (int r = 0; r < 4; r++) prw[r] = perm[base + quad * 4 + r];
        f32x4 acc[4];
#pragma unroll
        for (int i = 0; i < 4; i++) acc[i] = (f32x4){0.f, 0.f, 0.f, 0.f};
#pragma unroll
        for (int ks = 0; ks < 2; ks++) {
            int gp = (ks * 4 + quad) ^ (m & 7);
            bf16x8 a = *(const bf16x8*)&AT[wv][m][gp * 8];
            if (ks == 1 && quad == 3) a[7] = bf1(dv);   // k=63 column
#pragma unroll
            for (int tile = 0; tile < 4; tile++) {
                bf16x8 b = *(const bf16x8*)&SB[ks][tile][slot][0];
                acc[tile] = __builtin_amdgcn_mfma_f32_16x16x32_bf16(a, b, acc[tile], 0, 0, 0);
            }
        }
#pragma unroll
        for (int tile = 0; tile < 4; tile++)
#pragma unroll
            for (int r = 0; r < 4; r++)
                ee[(size_t)prw[r] * 64 + tile * 16 + m] =
                    (u16)bf1(fmaxf(acc[tile][r], 0.f));
    }
}

// fused gather + MPNN layer, degree-sorted tiles via perm. XT: agg tile for
// GEMM1 then msg tile for GEMM2 (disjoint lifetimes, 40KB LDS total).
template <bool F32OUT>
__global__ __launch_bounds__(256) void k_flayer(
        const u16* __restrict__ cur, const u16* __restrict__ ee,
        const int* __restrict__ rowptr, const u16* __restrict__ csr,
        const float* __restrict__ Wm, const float* __restrict__ Wu,
        const int* __restrict__ perm, void* __restrict__ outp) {
    __shared__ unsigned SB[2][4][4][64][4];   // 32KB
    __shared__ short XT[4][16][64];           // 8KB
    int t = threadIdx.x;
    for (int F = t; F < 2048; F += 256) {
        int g = F >> 10, ks = (F >> 8) & 3, tile = (F >> 6) & 3, ln = F & 63;
        int c = ln & 15, qq = ln >> 4;
        const float* W = (g ? Wu : Wm) + (ks * 32 + qq * 8) * 64 + tile * 16 + c;
        unsigned d0 = pkbf(W[0],      W[64]);
        unsigned d1 = pkbf(W[2 * 64], W[3 * 64]);
        unsigned d2 = pkbf(W[4 * 64], W[5 * 64]);
        unsigned d3 = pkbf(W[6 * 64], W[7 * 64]);
        int slot = ln ^ ((ln >> 3) & 7);
        SB[g][ks][tile][slot][0] = d0; SB[g][ks][tile][slot][1] = d1;
        SB[g][ks][tile][slot][2] = d2; SB[g][ks][tile][slot][3] = d3;
    }
    __syncthreads();
    int wv = t >> 6, lane = t & 63;
    int m = lane & 15, quad = lane >> 4;
    int slot = lane ^ ((lane >> 3) & 7);
    for (int tb = blockIdx.x * 4 + wv; tb < NTILES; tb += gridDim.x * 4) {
        int base = tb * 16;
        int pn = perm[base + m];
        gather_tile(cur, rowptr, csr, pn, m, quad, wv, XT);
        const u16* erow = ee  + (size_t)pn * 64;
        const u16* crow = cur + (size_t)pn * 64;
        int prw[4];
#pragma unroll
        for (int r = 0; r < 4; r++) prw[r] = perm[base + quad * 4 + r];
        f32x4 acc[4];
#pragma unroll
        for (int i = 0; i < 4; i++) acc[i] = (f32x4){0.f, 0.f, 0.f, 0.f};
        // GEMM1: k 0..63 = agg (XT), 64..127 = ee (global)
#pragma unroll
        for (int ks = 0; ks < 4; ks++) {
            bf16x8 a;
            if (ks < 2) {
                int gp = (ks * 4 + quad) ^ (m & 7);
                a = *(const bf16x8*)&XT[wv][m][gp * 8];
            } else {
                a = *(const bf16x8*)(erow + (ks - 2) * 32 + quad * 8);
            }
#pragma unroll
            for (int tile = 0; tile < 4; tile++) {
                bf16x8 b = *(const bf16x8*)&SB[0][ks][tile][slot][0];
                acc[tile] = __builtin_amdgcn_mfma_f32_16x16x32_bf16(a, b, acc[tile], 0, 0, 0);
            }
        }
        // relu(msg) -> XT (reuse) in A-readable swizzled layout (wave-private)
#pragma unroll
        for (int tile = 0; tile < 4; tile++)
#pragma unroll
            for (int r = 0; r < 4; r++) {
                int node = quad * 4 + r;
                int f = tile * 16 + m;
                int sidx = (((f >> 3) ^ (node & 7)) << 3) | (f & 7);
                XT[wv][node][sidx] = bf1(fmaxf(acc[tile][r], 0.f));
            }
        // GEMM2: k 0..63 = cur (global bf16), 64..127 = msg (XT)
#pragma unroll
        for (int i = 0; i < 4; i++) acc[i] = (f32x4){0.f, 0.f, 0.f, 0.f};
#pragma unroll
        for (int ks = 0; ks < 4; ks++) {
            bf16x8 a;
            if (ks < 2) {
                a = *(const bf16x8*)(crow + ks * 32 + quad * 8);
            } else {
                int gp = ((ks - 2) * 4 + quad) ^ (m & 7);
                a = *(const bf16x8*)&XT[wv][m][gp << 3];
            }
#pragma unroll
            for (int tile = 0; tile < 4; tile++) {
                bf16x8 b = *(const bf16x8*)&SB[1][ks][tile][slot][0];
                acc[tile] = __builtin_amdgcn_mfma_f32_16x16x32_bf16(a, b, acc[tile], 0, 0, 0);
            }
        }
#pragma unroll
        for (int tile = 0; tile < 4; tile++)
#pragma unroll
            for (int r = 0; r < 4; r++) {
                float v = fmaxf(acc[tile][r], 0.f);
                size_t oi = (size_t)prw[r] * 64 + tile * 16 + m;
                if (F32OUT) ((float*)outp)[oi] = v;
                else        ((u16*)outp)[oi] = (u16)bf1(v);
            }
    }
}

// R21: atomic-free means partials (distinct addresses, no done-counter).
__global__ __launch_bounds__(256) void k_means2(const float* __restrict__ cur,
                                                float* __restrict__ pmeans) {
    int g = blockIdx.x / MCHUNK;
    int c = blockIdx.x % MCHUNK;
    int t = threadIdx.x, f = t & 63, q = t >> 6;
    int base = g * NPG + c * MROWS;
    float acc = 0.f;
    for (int n = base + q; n < base + MROWS; n += 4) acc += cur[(size_t)n * 64 + f];
    __shared__ float red[4][64];
    red[q][f] = acc;
    __syncthreads();
    if (q == 0)
        pmeans[(size_t)(g * MCHUNK + c) * 64 + f] =
            red[0][f] + red[1][f] + red[2][f] + red[3][f];
}

// r1[g] = sum_f relu((mean[g] @ Wp)[f]) * Wr[f]. One block.
__global__ __launch_bounds__(256) void k_pool2(
        const float* __restrict__ pmeans, const float* __restrict__ Wp,
        const float* __restrict__ Wr, float* __restrict__ r1) {
    __shared__ float sm[4][64];
    int wv = threadIdx.x >> 6, lane = threadIdx.x & 63;
    for (int g = wv; g < NG; g += 4) {
        float m = 0.f;
        const float* pm = pmeans + (size_t)g * MCHUNK * 64 + lane;
#pragma unroll
        for (int c = 0; c < MCHUNK; c++) m += pm[c * 64];
        sm[wv][lane] = m * (1.0f / NPG);
        float a2 = 0.f;
#pragma unroll 16
        for (int k = 0; k < 64; k++) a2 = fmaf(sm[wv][k], Wp[k * 64 + lane], a2);
        float v = fmaxf(a2, 0.f) * Wr[lane];
        for (int off = 32; off; off >>= 1) v += __shfl_xor(v, off, 64);
        if (lane == 0) r1[g] = v;
    }
}

// out[n] = b + r1[batch[n]] + dot(relu(cur[n]), Wr[64:])
__global__ void k_read2(const float* __restrict__ cur, const float* __restrict__ r1,
                        const int* __restrict__ batch, const float* __restrict__ Wr,
                        const float* __restrict__ br, float* __restrict__ out) {
    int idx = blockIdx.x * 256 + threadIdx.x;
    int node = idx >> 4;
    if (node >= N_NODES) return;
    int q = idx & 15;
    float4 c = *(const float4*)(cur + (size_t)node * 64 + q * 4);
    float4 w = *(const float4*)(Wr + 64 + q * 4);
    float v = fmaxf(c.x, 0.f) * w.x + fmaxf(c.y, 0.f) * w.y
            + fmaxf(c.z, 0.f) * w.z + fmaxf(c.w, 0.f) * w.w;
    v += __shfl_xor(v, 1, 64); v += __shfl_xor(v, 2, 64);
    v += __shfl_xor(v, 4, 64); v += __shfl_xor(v, 8, 64);
    if (q == 0) out[node] = v + r1[batch[node]] + br[0];
}

// ---------------------------------------------------------------------------
extern "C" void kernel_launch(void* const* d_in, const int* in_sizes, int n_in,
                              void* d_out, int out_size, void* d_ws, size_t ws_size,
                              hipStream_t stream) {
    const float* x    = (const float*)d_in[0];
    const float* Wi   = (const float*)d_in[1];
    const float* We1  = (const float*)d_in[2];
    const float* We2  = (const float*)d_in[3];
    const float* Wm   = (const float*)d_in[4];   // [3,128,64]
    const float* Wu   = (const float*)d_in[5];   // [3,128,64]
    const float* Wp   = (const float*)d_in[6];
    const float* Wr   = (const float*)d_in[7];
    const float* br   = (const float*)d_in[8];
    const int*   ei   = (const int*)d_in[9];     // [2,E]
    const int*   batch= (const int*)d_in[10];
    const int* row = ei;
    const int* col = ei + N_EDGES;
    float* out = (float*)d_out;

    char* w = (char*)d_ws;
    size_t off = 0;
    auto carve = [&](size_t bytes) -> void* {
        void* p = (void*)(w + off);
        off += (bytes + 255) & ~(size_t)255;
        return p;
    };
    // zero-init region (one memset: deg + dmax + hist + binBump)
    int*   deg      = (int*)carve((size_t)N_NODES * 4 * 32);   // 128B line per node
    int*   dmax     = (int*)carve(256);
    int*   hist     = (int*)carve(256 * 4);
    int*   binBump  = (int*)carve(256 * 4);
    size_t zero_span = off;
    int*   rowptr   = (int*)carve((size_t)(N_NODES + 1) * 4);
    unsigned* qoff  = (unsigned*)carve((size_t)N_NODES * 4);
    u8*    epos     = (u8*)carve((size_t)N_EDGES);
    u16*   csr      = (u16*)carve((size_t)N_EDGES * 2);
    int*   partials = (int*)carve((size_t)SCAN_NBLK * 4);
    int*   perm     = (int*)carve((size_t)N_NODES * 4);
    float* pmeans   = (float*)carve((size_t)NG * MCHUNK * 64 * 4);
    u16*   bufA     = (u16*)carve((size_t)N_NODES * 64 * 2);
    u16*   bufB     = (u16*)carve((size_t)N_NODES * 64 * 2);
    u16*   ee       = (u16*)carve((size_t)N_NODES * 64 * 2);
    float* curF     = (float*)carve((size_t)N_NODES * 64 * 4);
    float* r1       = (float*)carve((size_t)NG * 4);

    hipMemsetAsync(d_ws, 0, zero_span, stream);

    // CSR build fused with node init (quarter-binned epos)
    k_deg_init<<<DEG_BLKS + INIT_BLKS, 256, 0, stream>>>(row, col, deg, epos,
                                                         x, Wi, We1, bufA, bufB);
    // spin-free scan + counting-sort perm + quarter offsets
    k_blocksum  <<<SCAN_NBLK, 256, 0, stream>>>(deg, partials, dmax, hist);
    k_scanfinal2<<<SCAN_NBLK, 256, 0, stream>>>(deg, partials, hist, rowptr,
                                                qoff, binBump, perm);
    // atomic-free streaming CSR fill (source-quarter-sorted lists)
    k_fill      <<<DEG_BLKS, 256, 0, stream>>>(row, col, rowptr, qoff, epos, csr);

    // fused h-gather + edge embedding (bufB = h)
    k_edge_f<<<GATHER_BLKS, 256, 0, stream>>>(bufB, rowptr, csr, dmax, We2, perm, ee);

    // fused gather+layer x3: A->B, B->A, A->curF(fp32)
    k_flayer<false><<<GATHER_BLKS, 256, 0, stream>>>(bufA, ee, rowptr, csr,
                                                     Wm, Wu, perm, bufB);
    k_flayer<false><<<GATHER_BLKS, 256, 0, stream>>>(bufB, ee, rowptr, csr,
                                                     Wm + 128 * 64, Wu + 128 * 64,
                                                     perm, bufA);
    k_flayer<true> <<<GATHER_BLKS, 256, 0, stream>>>(bufA, ee, rowptr, csr,
                                                     Wm + 2 * 128 * 64, Wu + 2 * 128 * 64,
                                                     perm, curF);

    // atomic-free means partials -> tiny pool kernel
    k_means2<<<NG * MCHUNK, 256, 0, stream>>>(curF, pmeans);
    k_pool2 <<<1, 256, 0, stream>>>(pmeans, Wp, Wr, r1);
    k_read2<<<(N_NODES * 16 + 255) / 256, 256, 0, stream>>>(curF, r1, batch, Wr, br, out);
}

// Round 11
// 296.859 us; speedup vs baseline: 1.0739x; 1.0474x over previous
//
#include <hip/hip_runtime.h>
#include <hip/hip_bf16.h>

#define N_NODES 50000
#define N_EDGES 800000
#define NF      64
#define NG      50
#define NPG     (N_NODES / NG)   // 1000 nodes per graph
#define SCAN_NBLK ((N_NODES + 255) / 256)   // 196
#define MCHUNK  20               // blocks per graph for means
#define MROWS   (NPG / MCHUNK)   // 50 nodes per means block
#define NTILES  (N_NODES / 16)   // 3125 exact
#define GATHER_BLKS ((NTILES + 3) / 4)      // 782: one tile per wave
#define FP_CHUNKS 896
#define FP_CHSZ  ((N_EDGES + FP_CHUNKS - 1) / FP_CHUNKS)   // 893
#define FP_NPP   (N_NODES / 8)   // 6250 nodes per partition
#define DEG_BLKS (FP_CHUNKS * 8) // 7168
#define INIT_BLKS ((N_NODES * 32 + 255) / 256)  // 6250
#define DEGS 5                   // deg stride shift: 32 ints = 128B per node

typedef __attribute__((ext_vector_type(8))) short bf16x8;
typedef __attribute__((ext_vector_type(4))) float f32x4;
typedef unsigned short u16;
typedef unsigned char u8;

// round-half-up fp32->bf16 pair pack (inputs are finite)
__device__ inline unsigned pkbf(float a, float b) {
    unsigned ua = __float_as_uint(a) + 0x8000u;
    unsigned ub = __float_as_uint(b) + 0x8000u;
    return (ua >> 16) | (ub & 0xFFFF0000u);
}
__device__ inline short bf1(float a) {
    return (short)((__float_as_uint(a) + 0x8000u) >> 16);
}
__device__ inline float lo2f(unsigned u) { return __uint_as_float(u << 16); }
__device__ inline float hi2f(unsigned u) { return __uint_as_float(u & 0xFFFF0000u); }
// packed accumulate: float2 adds -> v_pk_add_f32
__device__ inline void accp(float2* a, uint4 v) {
    a[0].x += lo2f(v.x); a[0].y += hi2f(v.x);
    a[1].x += lo2f(v.y); a[1].y += hi2f(v.y);
    a[2].x += lo2f(v.z); a[2].y += hi2f(v.z);
    a[3].x += lo2f(v.w); a[3].y += hi2f(v.w);
}

// ---------------------------------------------------------------------------
// FUSED: degree histogram (blocks [0,DEG_BLKS)) + node init embeddings.
// R19: histogram atomicAdd RETURNS the edge's CSR slot (epos) -> k_fill is
// atomic-free. R22: 800K atomics / 44us ~ device-atomic throughput ceiling.
// R24: quarter-sort (R23) REVERTED — neutral on gathers (per-quarter lists
// are only ~4 edges; no coherent window), cost deg_init +4.3us.
__global__ void k_deg_init(const int* __restrict__ col, int* __restrict__ deg,
                           u8* __restrict__ epos,
                           const float* __restrict__ x, const float* __restrict__ Wi,
                           const float* __restrict__ We1,
                           u16* __restrict__ cur, u16* __restrict__ h) {
    if (blockIdx.x < DEG_BLKS) {
        int part = blockIdx.x & 7, chunk = blockIdx.x >> 3;
        int lo = part * FP_NPP, hi = lo + FP_NPP;
        int e0 = chunk * FP_CHSZ;
        int e1 = min(N_EDGES, e0 + FP_CHSZ);
        for (int e = e0 + threadIdx.x; e < e1; e += 256) {
            int c = col[e];
            if (c >= lo && c < hi) {
                int pos = atomicAdd(&deg[c << DEGS], 1);
                epos[e] = (u8)pos;
            }
        }
        return;
    }
    int idx = (blockIdx.x - DEG_BLKS) * 256 + threadIdx.x;   // N*32
    int node = idx >> 5, q = idx & 31;
    if (node >= N_NODES) return;
    int f0 = 2 * q, f1 = 2 * q + 1;
    float4 xv = ((const float4*)x)[node];
    float c0 = xv.x * Wi[f0] + xv.y * Wi[64 + f0] + xv.z * Wi[128 + f0] + xv.w * Wi[192 + f0];
    float c1 = xv.x * Wi[f1] + xv.y * Wi[64 + f1] + xv.z * Wi[128 + f1] + xv.w * Wi[192 + f1];
    ((unsigned*)cur)[node * 32 + q] = pkbf(fmaxf(c0, 0.f), fmaxf(c1, 0.f));
    float h0 = xv.x * We1[f0] + xv.y * We1[63 + f0] + xv.z * We1[126 + f0] + xv.w * We1[189 + f0];
    h0 = fmaxf(h0, 0.f);
    float h1 = 0.f;
    if (f1 < 63) {
        h1 = xv.x * We1[f1] + xv.y * We1[63 + f1] + xv.z * We1[126 + f1] + xv.w * We1[189 + f1];
        h1 = fmaxf(h1, 0.f);
    }
    ((unsigned*)h)[node * 32 + q] = pkbf(h0, h1);
}

// ---------------------------------------------------------------------------
// Spin-free scan (R16: never spin across blocks) + degree histogram for the
// counting sort (R17).
__global__ void k_blocksum(const int* __restrict__ deg, int* __restrict__ partials,
                           int* __restrict__ dmax, int* __restrict__ hist) {
    __shared__ int lh[256];
    int t = threadIdx.x;
    lh[t] = 0;
    __syncthreads();
    int i = blockIdx.x * 256 + t;
    int d = (i < N_NODES) ? deg[i << DEGS] : 0;
    if (i < N_NODES) atomicAdd(&lh[min(d, 255)], 1);
    int v = d, m = d;
    for (int off = 32; off; off >>= 1) {
        v += __shfl_xor(v, off, 64);
        m = max(m, __shfl_xor(m, off, 64));
    }
    __shared__ int s[4];
    if ((t & 63) == 0) { s[t >> 6] = v; atomicMax(dmax, m); }
    __syncthreads();
    if (t == 0) partials[blockIdx.x] = s[0] + s[1] + s[2] + s[3];
    if (lh[t]) atomicAdd(&hist[t], lh[t]);
}

// Exclusive scan over deg -> rowptr, two-level counting-sort scatter (R18).
// R24: perm is DESCENDING-degree (bin base = total - inclusive prefix):
// high-degree tiles are processed FIRST, so the straggler tail of each
// gather kernel is the SHORTEST lists instead of the longest (~2.5x mean).
__global__ __launch_bounds__(256) void k_scanfinal2(
        const int* __restrict__ deg, const int* __restrict__ partials,
        const int* __restrict__ hist, int* __restrict__ rowptr,
        int* __restrict__ binBump, int* __restrict__ perm) {
    int b = blockIdx.x, t = threadIdx.x;
    __shared__ int lh[256], lbase[256];
    lh[t] = 0;
    // prev = sum of partials[0..b)
    int p = (t < b) ? partials[t] : 0;     // b <= 195 < 256
    for (int off = 32; off; off >>= 1) p += __shfl_xor(p, off, 64);
    __shared__ int sr[4];
    if ((t & 63) == 0) sr[t >> 6] = p;
    __syncthreads();                        // sr ready + lh zeroed
    int prev = sr[0] + sr[1] + sr[2] + sr[3];
    int i = b * 256 + t;
    int v = (i < N_NODES) ? deg[i << DEGS] : 0;
    int bin = min(v, 255);
    int rank = 0;
    if (i < N_NODES) rank = atomicAdd(&lh[bin], 1);   // LDS atomic: local rank
    __shared__ int s[256];
    // scan 1: inclusive prefix of hist -> descending bin bases
    int hv = hist[t];
    s[t] = hv;
    __syncthreads();
    for (int off = 1; off < 256; off <<= 1) {
        int u = (t >= off) ? s[t - off] : 0;
        __syncthreads();
        s[t] += u;
        __syncthreads();
    }
    int total = s[255];
    int hpref = total - s[t];   // base for bin t in DESCENDING-degree order
    // scan 2: local exclusive scan of deg
    __syncthreads();
    s[t] = v;
    __syncthreads();
    for (int off = 1; off < 256; off <<= 1) {
        int u = (t >= off) ? s[t - off] : 0;
        __syncthreads();
        s[t] += u;
        __syncthreads();
    }
    int ex = prev + s[t] - v;
    if (i < N_NODES) rowptr[i] = ex;
    if (b == 0 && t == 0) rowptr[N_NODES] = N_EDGES;
    // one global atomic per non-empty bin -> block base in that bin
    __syncthreads();
    if (lh[t] > 0) lbase[t] = hpref + atomicAdd(&binBump[t], lh[t]);
    __syncthreads();
    if (i < N_NODES) perm[lbase[bin] + rank] = i;
}

// CSR fill: ATOMIC-FREE streaming (R19) — slot comes from epos computed in
// the deg pass. Destination-partitioned so csr writes stay XCD-local.
__global__ void k_fill(const int* __restrict__ row, const int* __restrict__ col,
                       const int* __restrict__ rowptr, const u8* __restrict__ epos,
                       u16* __restrict__ csr) {
    int part = blockIdx.x & 7, chunk = blockIdx.x >> 3;
    int lo = part * FP_NPP, hi = lo + FP_NPP;
    int e0 = chunk * FP_CHSZ;
    int e1 = min(N_EDGES, e0 + FP_CHSZ);
    for (int e = e0 + threadIdx.x; e < e1; e += 256) {
        int c = col[e];
        if (c >= lo && c < hi)
            csr[rowptr[c] + epos[e]] = (u16)row[e];
    }
}

// Per-wave fused gather. R24: 6-edge software pipeline — 12 uint4 in flight
// per lane (+50% MLP vs depth 4). The gather is pinned by per-lane in-flight
// count (R4 occupancy-null, R9 de-fuse-null, R23 L2-window-null). Register
// budget: 48 in-flight + 16 acc + ~30 misc ~= 100 VGPR, single acc bank —
// unlike R15's depth-8 x 2-bank (96 data VGPR) which spilled. If WRITE_SIZE
// balloons -> spill -> revert to depth 4.
__device__ inline void gather_tile(const u16* __restrict__ src,
                                   const int* __restrict__ rowptr,
                                   const u16* __restrict__ csr,
                                   int node, int m, int q, int wv,
                                   short (*AT)[16][64]) {
    int beg = rowptr[node], end = rowptr[node + 1];
    float2 ac[8];
#pragma unroll
    for (int i = 0; i < 8; i++) ac[i] = make_float2(0.f, 0.f);
    int j = beg;
    for (; j + 5 < end; j += 6) {
        int r0 = csr[j],     r1 = csr[j + 1], r2 = csr[j + 2];
        int r3 = csr[j + 3], r4 = csr[j + 4], r5 = csr[j + 5];
        const uint4* p0 = (const uint4*)(src + (size_t)r0 * 64 + q * 16);
        const uint4* p1 = (const uint4*)(src + (size_t)r1 * 64 + q * 16);
        const uint4* p2 = (const uint4*)(src + (size_t)r2 * 64 + q * 16);
        const uint4* p3 = (const uint4*)(src + (size_t)r3 * 64 + q * 16);
        const uint4* p4 = (const uint4*)(src + (size_t)r4 * 64 + q * 16);
        const uint4* p5 = (const uint4*)(src + (size_t)r5 * 64 + q * 16);
        uint4 v00 = p0[0], v01 = p0[1];
        uint4 v10 = p1[0], v11 = p1[1];
        uint4 v20 = p2[0], v21 = p2[1];
        uint4 v30 = p3[0], v31 = p3[1];
        uint4 v40 = p4[0], v41 = p4[1];
        uint4 v50 = p5[0], v51 = p5[1];
        accp(ac, v00); accp(ac + 4, v01);
        accp(ac, v10); accp(ac + 4, v11);
        accp(ac, v20); accp(ac + 4, v21);
        accp(ac, v30); accp(ac + 4, v31);
        accp(ac, v40); accp(ac + 4, v41);
        accp(ac, v50); accp(ac + 4, v51);
    }
    for (; j + 3 < end; j += 4) {
        int r0 = csr[j], r1 = csr[j + 1], r2 = csr[j + 2], r3 = csr[j + 3];
        const uint4* p0 = (const uint4*)(src + (size_t)r0 * 64 + q * 16);
        const uint4* p1 = (const uint4*)(src + (size_t)r1 * 64 + q * 16);
        const uint4* p2 = (const uint4*)(src + (size_t)r2 * 64 + q * 16);
        const uint4* p3 = (const uint4*)(src + (size_t)r3 * 64 + q * 16);
        uint4 v00 = p0[0], v01 = p0[1];
        uint4 v10 = p1[0], v11 = p1[1];
        uint4 v20 = p2[0], v21 = p2[1];
        uint4 v30 = p3[0], v31 = p3[1];
        accp(ac, v00); accp(ac + 4, v01);
        accp(ac, v10); accp(ac + 4, v11);
        accp(ac, v20); accp(ac + 4, v21);
        accp(ac, v30); accp(ac + 4, v31);
    }
    for (; j < end; j++) {
        int r = csr[j];
        const uint4* p = (const uint4*)(src + (size_t)r * 64 + q * 16);
        uint4 v0 = p[0], v1 = p[1];
        accp(ac, v0); accp(ac + 4, v1);
    }
    float inv = 1.0f / (float)(end - beg);   // deg > 0 always
    uint4 lo, hi;
    lo.x = pkbf(ac[0].x * inv, ac[0].y * inv);
    lo.y = pkbf(ac[1].x * inv, ac[1].y * inv);
    lo.z = pkbf(ac[2].x * inv, ac[2].y * inv);
    lo.w = pkbf(ac[3].x * inv, ac[3].y * inv);
    hi.x = pkbf(ac[4].x * inv, ac[4].y * inv);
    hi.y = pkbf(ac[5].x * inv, ac[5].y * inv);
    hi.z = pkbf(ac[6].x * inv, ac[6].y * inv);
    hi.w = pkbf(ac[7].x * inv, ac[7].y * inv);
    *(uint4*)&AT[wv][m][((2 * q) ^ (m & 7)) * 8]     = lo;
    *(uint4*)&AT[wv][m][((2 * q + 1) ^ (m & 7)) * 8] = hi;
}

// fused h-gather + edge_emb MFMA, degree-sorted tiles via perm.
__global__ __launch_bounds__(256) void k_edge_f(
        const u16* __restrict__ h, const int* __restrict__ rowptr,
        const u16* __restrict__ csr, const int* __restrict__ dmax,
        const float* __restrict__ We2, const int* __restrict__ perm,
        u16* __restrict__ ee) {
    __shared__ unsigned SB[2][4][64][4];   // 8KB
    __shared__ short AT[4][16][64];        // 8KB
    int t = threadIdx.x;
    for (int F = t; F < 512; F += 256) {
        int ks = F >> 8, tile = (F >> 6) & 3, ln = F & 63;
        int c = ln & 15, qq = ln >> 4;
        const float* W = We2 + (ks * 32 + qq * 8) * 64 + tile * 16 + c;
        unsigned d0 = pkbf(W[0],       W[64]);
        unsigned d1 = pkbf(W[2 * 64],  W[3 * 64]);
        unsigned d2 = pkbf(W[4 * 64],  W[5 * 64]);
        unsigned d3 = pkbf(W[6 * 64],  W[7 * 64]);
        int slot = ln ^ ((ln >> 3) & 7);
        SB[ks][tile][slot][0] = d0; SB[ks][tile][slot][1] = d1;
        SB[ks][tile][slot][2] = d2; SB[ks][tile][slot][3] = d3;
    }
    __syncthreads();
    int wv = t >> 6, lane = t & 63;
    int m = lane & 15, quad = lane >> 4;
    int slot = lane ^ ((lane >> 3) & 7);
    float idm = 1.0f / (float)dmax[0];
    for (int tb = blockIdx.x * 4 + wv; tb < NTILES; tb += gridDim.x * 4) {
        int base = tb * 16;
        int pn = perm[base + m];
        gather_tile(h, rowptr, csr, pn, m, quad, wv, AT);
        float dv = (float)(rowptr[pn + 1] - rowptr[pn]) * idm;
        int prw[4];
#pragma unroll
        for (int r = 0; r < 4; r++) prw[r] = perm[base + quad * 4 + r];
        f32x4 acc[4];
#pragma unroll
        for (int i = 0; i < 4; i++) acc[i] = (f32x4){0.f, 0.f, 0.f, 0.f};
#pragma unroll
        for (int ks = 0; ks < 2; ks++) {
            int gp = (ks * 4 + quad) ^ (m & 7);
            bf16x8 a = *(const bf16x8*)&AT[wv][m][gp * 8];
            if (ks == 1 && quad == 3) a[7] = bf1(dv);   // k=63 column
#pragma unroll
            for (int tile = 0; tile < 4; tile++) {
                bf16x8 b = *(const bf16x8*)&SB[ks][tile][slot][0];
                acc[tile] = __builtin_amdgcn_mfma_f32_16x16x32_bf16(a, b, acc[tile], 0, 0, 0);
            }
        }
#pragma unroll
        for (int tile = 0; tile < 4; tile++)
#pragma unroll
            for (int r = 0; r < 4; r++)
                ee[(size_t)prw[r] * 64 + tile * 16 + m] =
                    (u16)bf1(fmaxf(acc[tile][r], 0.f));
    }
}

// fused gather + MPNN layer, degree-sorted tiles via perm. XT: agg tile for
// GEMM1 then msg tile for GEMM2 (disjoint lifetimes, 40KB LDS total).
template <bool F32OUT>
__global__ __launch_bounds__(256) void k_flayer(
        const u16* __restrict__ cur, const u16* __restrict__ ee,
        const int* __restrict__ rowptr, const u16* __restrict__ csr,
        const float* __restrict__ Wm, const float* __restrict__ Wu,
        const int* __restrict__ perm, void* __restrict__ outp) {
    __shared__ unsigned SB[2][4][4][64][4];   // 32KB
    __shared__ short XT[4][16][64];           // 8KB
    int t = threadIdx.x;
    for (int F = t; F < 2048; F += 256) {
        int g = F >> 10, ks = (F >> 8) & 3, tile = (F >> 6) & 3, ln = F & 63;
        int c = ln & 15, qq = ln >> 4;
        const float* W = (g ? Wu : Wm) + (ks * 32 + qq * 8) * 64 + tile * 16 + c;
        unsigned d0 = pkbf(W[0],      W[64]);
        unsigned d1 = pkbf(W[2 * 64], W[3 * 64]);
        unsigned d2 = pkbf(W[4 * 64], W[5 * 64]);
        unsigned d3 = pkbf(W[6 * 64], W[7 * 64]);
        int slot = ln ^ ((ln >> 3) & 7);
        SB[g][ks][tile][slot][0] = d0; SB[g][ks][tile][slot][1] = d1;
        SB[g][ks][tile][slot][2] = d2; SB[g][ks][tile][slot][3] = d3;
    }
    __syncthreads();
    int wv = t >> 6, lane = t & 63;
    int m = lane & 15, quad = lane >> 4;
    int slot = lane ^ ((lane >> 3) & 7);
    for (int tb = blockIdx.x * 4 + wv; tb < NTILES; tb += gridDim.x * 4) {
        int base = tb * 16;
        int pn = perm[base + m];
        gather_tile(cur, rowptr, csr, pn, m, quad, wv, XT);
        const u16* erow = ee  + (size_t)pn * 64;
        const u16* crow = cur + (size_t)pn * 64;
        int prw[4];
#pragma unroll
        for (int r = 0; r < 4; r++) prw[r] = perm[base + quad * 4 + r];
        f32x4 acc[4];
#pragma unroll
        for (int i = 0; i < 4; i++) acc[i] = (f32x4){0.f, 0.f, 0.f, 0.f};
        // GEMM1: k 0..63 = agg (XT), 64..127 = ee (global)
#pragma unroll
        for (int ks = 0; ks < 4; ks++) {
            bf16x8 a;
            if (ks < 2) {
                int gp = (ks * 4 + quad) ^ (m & 7);
                a = *(const bf16x8*)&XT[wv][m][gp * 8];
            } else {
                a = *(const bf16x8*)(erow + (ks - 2) * 32 + quad * 8);
            }
#pragma unroll
            for (int tile = 0; tile < 4; tile++) {
                bf16x8 b = *(const bf16x8*)&SB[0][ks][tile][slot][0];
                acc[tile] = __builtin_amdgcn_mfma_f32_16x16x32_bf16(a, b, acc[tile], 0, 0, 0);
            }
        }
        // relu(msg) -> XT (reuse) in A-readable swizzled layout (wave-private)
#pragma unroll
        for (int tile = 0; tile < 4; tile++)
#pragma unroll
            for (int r = 0; r < 4; r++) {
                int node = quad * 4 + r;
                int f = tile * 16 + m;
                int sidx = (((f >> 3) ^ (node & 7)) << 3) | (f & 7);
                XT[wv][node][sidx] = bf1(fmaxf(acc[tile][r], 0.f));
            }
        // GEMM2: k 0..63 = cur (global bf16), 64..127 = msg (XT)
#pragma unroll
        for (int i = 0; i < 4; i++) acc[i] = (f32x4){0.f, 0.f, 0.f, 0.f};
#pragma unroll
        for (int ks = 0; ks < 4; ks++) {
            bf16x8 a;
            if (ks < 2) {
                a = *(const bf16x8*)(crow + ks * 32 + quad * 8);
            } else {
                int gp = ((ks - 2) * 4 + quad) ^ (m & 7);
                a = *(const bf16x8*)&XT[wv][m][gp << 3];
            }
#pragma unroll
            for (int tile = 0; tile < 4; tile++) {
                bf16x8 b = *(const bf16x8*)&SB[1][ks][tile][slot][0];
                acc[tile] = __builtin_amdgcn_mfma_f32_16x16x32_bf16(a, b, acc[tile], 0, 0, 0);
            }
        }
#pragma unroll
        for (int tile = 0; tile < 4; tile++)
#pragma unroll
            for (int r = 0; r < 4; r++) {
                float v = fmaxf(acc[tile][r], 0.f);
                size_t oi = (size_t)prw[r] * 64 + tile * 16 + m;
                if (F32OUT) ((float*)outp)[oi] = v;
                else        ((u16*)outp)[oi] = (u16)bf1(v);
            }
    }
}

// R21: atomic-free means partials (distinct addresses, no done-counter).
__global__ __launch_bounds__(256) void k_means2(const float* __restrict__ cur,
                                                float* __restrict__ pmeans) {
    int g = blockIdx.x / MCHUNK;
    int c = blockIdx.x % MCHUNK;
    int t = threadIdx.x, f = t & 63, q = t >> 6;
    int base = g * NPG + c * MROWS;
    float acc = 0.f;
    for (int n = base + q; n < base + MROWS; n += 4) acc += cur[(size_t)n * 64 + f];
    __shared__ float red[4][64];
    red[q][f] = acc;
    __syncthreads();
    if (q == 0)
        pmeans[(size_t)(g * MCHUNK + c) * 64 + f] =
            red[0][f] + red[1][f] + red[2][f] + red[3][f];
}

// r1[g] = sum_f relu((mean[g] @ Wp)[f]) * Wr[f]. One block.
__global__ __launch_bounds__(256) void k_pool2(
        const float* __restrict__ pmeans, const float* __restrict__ Wp,
        const float* __restrict__ Wr, float* __restrict__ r1) {
    __shared__ float sm[4][64];
    int wv = threadIdx.x >> 6, lane = threadIdx.x & 63;
    for (int g = wv; g < NG; g += 4) {
        float m = 0.f;
        const float* pm = pmeans + (size_t)g * MCHUNK * 64 + lane;
#pragma unroll
        for (int c = 0; c < MCHUNK; c++) m += pm[c * 64];
        sm[wv][lane] = m * (1.0f / NPG);
        float a2 = 0.f;
#pragma unroll 16
        for (int k = 0; k < 64; k++) a2 = fmaf(sm[wv][k], Wp[k * 64 + lane], a2);
        float v = fmaxf(a2, 0.f) * Wr[lane];
        for (int off = 32; off; off >>= 1) v += __shfl_xor(v, off, 64);
        if (lane == 0) r1[g] = v;
    }
}

// out[n] = b + r1[batch[n]] + dot(relu(cur[n]), Wr[64:])
__global__ void k_read2(const float* __restrict__ cur, const float* __restrict__ r1,
                        const int* __restrict__ batch, const float* __restrict__ Wr,
                        const float* __restrict__ br, float* __restrict__ out) {
    int idx = blockIdx.x * 256 + threadIdx.x;
    int node = idx >> 4;
    if (node >= N_NODES) return;
    int q = idx & 15;
    float4 c = *(const float4*)(cur + (size_t)node * 64 + q * 4);
    float4 w = *(const float4*)(Wr + 64 + q * 4);
    float v = fmaxf(c.x, 0.f) * w.x + fmaxf(c.y, 0.f) * w.y
            + fmaxf(c.z, 0.f) * w.z + fmaxf(c.w, 0.f) * w.w;
    v += __shfl_xor(v, 1, 64); v += __shfl_xor(v, 2, 64);
    v += __shfl_xor(v, 4, 64); v += __shfl_xor(v, 8, 64);
    if (q == 0) out[node] = v + r1[batch[node]] + br[0];
}

// ---------------------------------------------------------------------------
extern "C" void kernel_launch(void* const* d_in, const int* in_sizes, int n_in,
                              void* d_out, int out_size, void* d_ws, size_t ws_size,
                              hipStream_t stream) {
    const float* x    = (const float*)d_in[0];
    const float* Wi   = (const float*)d_in[1];
    const float* We1  = (const float*)d_in[2];
    const float* We2  = (const float*)d_in[3];
    const float* Wm   = (const float*)d_in[4];   // [3,128,64]
    const float* Wu   = (const float*)d_in[5];   // [3,128,64]
    const float* Wp   = (const float*)d_in[6];
    const float* Wr   = (const float*)d_in[7];
    const float* br   = (const float*)d_in[8];
    const int*   ei   = (const int*)d_in[9];     // [2,E]
    const int*   batch= (const int*)d_in[10];
    const int* row = ei;
    const int* col = ei + N_EDGES;
    float* out = (float*)d_out;

    char* w = (char*)d_ws;
    size_t off = 0;
    auto carve = [&](size_t bytes) -> void* {
        void* p = (void*)(w + off);
        off += (bytes + 255) & ~(size_t)255;
        return p;
    };
    // zero-init region (one memset: deg + dmax + hist + binBump)
    int*   deg      = (int*)carve((size_t)N_NODES * 4 * 32);   // 128B line per node
    int*   dmax     = (int*)carve(256);
    int*   hist     = (int*)carve(256 * 4);
    int*   binBump  = (int*)carve(256 * 4);
    size_t zero_span = off;
    int*   rowptr   = (int*)carve((size_t)(N_NODES + 1) * 4);
    u8*    epos     = (u8*)carve((size_t)N_EDGES);
    u16*   csr      = (u16*)carve((size_t)N_EDGES * 2);
    int*   partials = (int*)carve((size_t)SCAN_NBLK * 4);
    int*   perm     = (int*)carve((size_t)N_NODES * 4);
    float* pmeans   = (float*)carve((size_t)NG * MCHUNK * 64 * 4);
    u16*   bufA     = (u16*)carve((size_t)N_NODES * 64 * 2);
    u16*   bufB     = (u16*)carve((size_t)N_NODES * 64 * 2);
    u16*   ee       = (u16*)carve((size_t)N_NODES * 64 * 2);
    float* curF     = (float*)carve((size_t)N_NODES * 64 * 4);
    float* r1       = (float*)carve((size_t)NG * 4);

    hipMemsetAsync(d_ws, 0, zero_span, stream);

    // CSR build fused with node init (epos = slot within node's segment)
    k_deg_init<<<DEG_BLKS + INIT_BLKS, 256, 0, stream>>>(col, deg, epos,
                                                         x, Wi, We1, bufA, bufB);
    // spin-free scan + counting-sort perm (descending degree)
    k_blocksum  <<<SCAN_NBLK, 256, 0, stream>>>(deg, partials, dmax, hist);
    k_scanfinal2<<<SCAN_NBLK, 256, 0, stream>>>(deg, partials, hist, rowptr,
                                                binBump, perm);
    // atomic-free streaming CSR fill
    k_fill      <<<DEG_BLKS, 256, 0, stream>>>(row, col, rowptr, epos, csr);

    // fused h-gather + edge embedding (bufB = h)
    k_edge_f<<<GATHER_BLKS, 256, 0, stream>>>(bufB, rowptr, csr, dmax, We2, perm, ee);

    // fused gather+layer x3: A->B, B->A, A->curF(fp32)
    k_flayer<false><<<GATHER_BLKS, 256, 0, stream>>>(bufA, ee, rowptr, csr,
                                                     Wm, Wu, perm, bufB);
    k_flayer<false><<<GATHER_BLKS, 256, 0, stream>>>(bufB, ee, rowptr, csr,
                                                     Wm + 128 * 64, Wu + 128 * 64,
                                                     perm, bufA);
    k_flayer<true> <<<GATHER_BLKS, 256, 0, stream>>>(bufA, ee, rowptr, csr,
                                                     Wm + 2 * 128 * 64, Wu + 2 * 128 * 64,
                                                     perm, curF);

    // atomic-free means partials -> tiny pool kernel
    k_means2<<<NG * MCHUNK, 256, 0, stream>>>(curF, pmeans);
    k_pool2 <<<1, 256, 0, stream>>>(pmeans, Wp, Wr, r1);
    k_read2<<<(N_NODES * 16 + 255) / 256, 256, 0, stream>>>(curF, r1, batch, Wr, br, out);
}

// Round 12
// 262.075 us; speedup vs baseline: 1.2164x; 1.1327x over previous
//
#include <hip/hip_runtime.h>
#include <hip/hip_bf16.h>

#define N_NODES 50000
#define N_EDGES 800000
#define NF      64
#define NG      50
#define NPG     (N_NODES / NG)   // 1000 nodes per graph
#define SCAN_NBLK ((N_NODES + 255) / 256)   // 196
#define MCHUNK  20               // blocks per graph for means
#define MROWS   (NPG / MCHUNK)   // 50 nodes per means block
#define NTILES  (N_NODES / 16)   // 3125 exact
#define GATHER_BLKS ((NTILES + 3) / 4)      // 782: one tile per wave
#define INIT_BLKS ((N_NODES * 32 + 255) / 256)  // 6250
// R25 bucket-radix CSR build (replaces 800K-atomic deg+fill, R22 ceiling):
#define NBKT ((N_NODES + 255) / 256)   // 196 coarse buckets (col>>8)
#define BKT_CAP 6144                   // mean 4096, sigma ~62 -> +33 sigma
#define P1_EPB 4096                    // edges per pass-1 block
#define P1_BLKS ((N_EDGES + P1_EPB - 1) / P1_EPB)   // 196

typedef __attribute__((ext_vector_type(8))) short bf16x8;
typedef __attribute__((ext_vector_type(4))) float f32x4;
typedef unsigned short u16;
typedef unsigned char u8;

// round-half-up fp32->bf16 pair pack (inputs are finite)
__device__ inline unsigned pkbf(float a, float b) {
    unsigned ua = __float_as_uint(a) + 0x8000u;
    unsigned ub = __float_as_uint(b) + 0x8000u;
    return (ua >> 16) | (ub & 0xFFFF0000u);
}
__device__ inline short bf1(float a) {
    return (short)((__float_as_uint(a) + 0x8000u) >> 16);
}
__device__ inline float lo2f(unsigned u) { return __uint_as_float(u << 16); }
__device__ inline float hi2f(unsigned u) { return __uint_as_float(u & 0xFFFF0000u); }
// packed accumulate: float2 adds -> v_pk_add_f32
__device__ inline void accp(float2* a, uint4 v) {
    a[0].x += lo2f(v.x); a[0].y += hi2f(v.x);
    a[1].x += lo2f(v.y); a[1].y += hi2f(v.y);
    a[2].x += lo2f(v.z); a[2].y += hi2f(v.z);
    a[3].x += lo2f(v.w); a[3].y += hi2f(v.w);
}

// ---------------------------------------------------------------------------
// R25 pass 1: bucket edges by col>>8 into fixed-stride regions. Per-edge
// work uses LDS atomics only; ONE global atomic per (block, non-empty
// bucket) ~ 38K total (vs 800K device atomics at the R22 ~7.6 RMW/cy
// ceiling = 44us). Init embeddings fused as extra blocks (unchanged).
__global__ void k_bucket_init(const int* __restrict__ row, const int* __restrict__ col,
                              int* __restrict__ bktCnt, unsigned* __restrict__ bktData,
                              const float* __restrict__ x, const float* __restrict__ Wi,
                              const float* __restrict__ We1,
                              u16* __restrict__ cur, u16* __restrict__ h) {
    if (blockIdx.x < P1_BLKS) {
        __shared__ int lh[256], lbase[256];
        int t = threadIdx.x;
        lh[t] = 0;
        __syncthreads();
        int e0 = blockIdx.x * P1_EPB;
        int myb[16], myr[16];
        unsigned mypk[16];
#pragma unroll
        for (int i = 0; i < 16; i++) {
            int e = e0 + i * 256 + t;
            myb[i] = -1;
            if (e < N_EDGES) {
                int c = col[e];
                mypk[i] = ((unsigned)c << 16) | (unsigned)row[e];
                int b = c >> 8;
                myb[i] = b;
                myr[i] = atomicAdd(&lh[b], 1);   // LDS: rank within block+bucket
            }
        }
        __syncthreads();
        if (lh[t] > 0) lbase[t] = atomicAdd(&bktCnt[t], lh[t]);
        __syncthreads();
#pragma unroll
        for (int i = 0; i < 16; i++)
            if (myb[i] >= 0)
                bktData[(size_t)myb[i] * BKT_CAP + lbase[myb[i]] + myr[i]] = mypk[i];
        return;
    }
    int idx = (blockIdx.x - P1_BLKS) * 256 + threadIdx.x;   // N*32
    int node = idx >> 5, q = idx & 31;
    if (node >= N_NODES) return;
    int f0 = 2 * q, f1 = 2 * q + 1;
    float4 xv = ((const float4*)x)[node];
    float c0 = xv.x * Wi[f0] + xv.y * Wi[64 + f0] + xv.z * Wi[128 + f0] + xv.w * Wi[192 + f0];
    float c1 = xv.x * Wi[f1] + xv.y * Wi[64 + f1] + xv.z * Wi[128 + f1] + xv.w * Wi[192 + f1];
    ((unsigned*)cur)[node * 32 + q] = pkbf(fmaxf(c0, 0.f), fmaxf(c1, 0.f));
    float h0 = xv.x * We1[f0] + xv.y * We1[63 + f0] + xv.z * We1[126 + f0] + xv.w * We1[189 + f0];
    h0 = fmaxf(h0, 0.f);
    float h1 = 0.f;
    if (f1 < 63) {
        h1 = xv.x * We1[f1] + xv.y * We1[63 + f1] + xv.z * We1[126 + f1] + xv.w * We1[189 + f1];
        h1 = fmaxf(h1, 0.f);
    }
    ((unsigned*)h)[node * 32 + q] = pkbf(h0, h1);
}

// R25 pass 2: block b sorts bucket b (cols [b*256, b*256+256)) by col&255
// entirely in LDS; writes deg (dense), rowptr, and csr. Zero per-edge global
// atomics. Global edge base = sum bktCnt[0..b) (spin-free per-block prefix,
// same pattern as the R16 scan).
__global__ __launch_bounds__(256) void k_bsort(
        const unsigned* __restrict__ bktData, const int* __restrict__ bktCnt,
        int* __restrict__ deg, int* __restrict__ rowptr, u16* __restrict__ csr) {
    int b = blockIdx.x, t = threadIdx.x;
    int cnt = bktCnt[b];
    int p = (t < b) ? bktCnt[t] : 0;     // b <= 195 < 256
    for (int off = 32; off; off >>= 1) p += __shfl_xor(p, off, 64);
    __shared__ int sr[4];
    if ((t & 63) == 0) sr[t >> 6] = p;
    __shared__ int lh[256];
    lh[t] = 0;
    __syncthreads();
    int prev = sr[0] + sr[1] + sr[2] + sr[3];
    const unsigned* bd = bktData + (size_t)b * BKT_CAP;
    for (int i = t; i < cnt; i += 256)
        atomicAdd(&lh[(bd[i] >> 16) & 255], 1);
    __syncthreads();
    int myh = lh[t];
    __shared__ int s[256];
    s[t] = myh;
    __syncthreads();
    for (int off = 1; off < 256; off <<= 1) {
        int u = (t >= off) ? s[t - off] : 0;
        __syncthreads();
        s[t] += u;
        __syncthreads();
    }
    __shared__ int lof[256];
    lof[t] = s[t] - myh;                 // exclusive offset within bucket
    int node = b * 256 + t;
    if (node < N_NODES) { deg[node] = myh; rowptr[node] = prev + lof[t]; }
    if (b == 0 && t == 0) rowptr[N_NODES] = N_EDGES;
    __shared__ int cur[256];
    cur[t] = 0;
    __syncthreads();
    for (int i = t; i < cnt; i += 256) {
        unsigned pk = bd[i];
        int ln = (pk >> 16) & 255;
        int pos = atomicAdd(&cur[ln], 1);  // LDS
        csr[prev + lof[ln] + pos] = (u16)(pk & 0xFFFFu);
    }
}

// ---------------------------------------------------------------------------
// dmax + degree histogram for the counting sort (deg is dense now).
__global__ void k_blocksum(const int* __restrict__ deg,
                           int* __restrict__ dmax, int* __restrict__ hist) {
    __shared__ int lh[256];
    int t = threadIdx.x;
    lh[t] = 0;
    __syncthreads();
    int i = blockIdx.x * 256 + t;
    int d = (i < N_NODES) ? deg[i] : 0;
    if (i < N_NODES) atomicAdd(&lh[min(d, 255)], 1);
    int m = d;
    for (int off = 32; off; off >>= 1) m = max(m, __shfl_xor(m, off, 64));
    if ((t & 63) == 0) atomicMax(dmax, m);
    __syncthreads();
    if (lh[t]) atomicAdd(&hist[t], lh[t]);
}

// Two-level counting-sort perm (R18 pattern), DESCENDING degree (R24: the
// straggler tail of each gather kernel is the shortest lists).
__global__ __launch_bounds__(256) void k_permsort(
        const int* __restrict__ deg, const int* __restrict__ hist,
        int* __restrict__ binBump, int* __restrict__ perm) {
    int b = blockIdx.x, t = threadIdx.x;
    __shared__ int lh[256], lbase[256];
    lh[t] = 0;
    __syncthreads();
    int i = b * 256 + t;
    int v = (i < N_NODES) ? deg[i] : 0;
    int bin = min(v, 255);
    int rank = 0;
    if (i < N_NODES) rank = atomicAdd(&lh[bin], 1);   // LDS: local rank
    __shared__ int s[256];
    int hv = hist[t];
    s[t] = hv;
    __syncthreads();
    for (int off = 1; off < 256; off <<= 1) {
        int u = (t >= off) ? s[t - off] : 0;
        __syncthreads();
        s[t] += u;
        __syncthreads();
    }
    int total = s[255];
    int hpref = total - s[t];   // base for bin t in DESCENDING-degree order
    if (lh[t] > 0) lbase[t] = hpref + atomicAdd(&binBump[t], lh[t]);
    __syncthreads();
    if (i < N_NODES) perm[lbase[bin] + rank] = i;
}

// Per-wave fused gather. R24: 6-edge software pipeline — 12 uint4 in flight
// per lane. The gather is pinned by per-lane in-flight count (R4 occupancy-
// null, R9 de-fuse-null, R23 L2-window-null). ~100 VGPR, single acc bank —
// R15's depth-8 x 2-bank spilled; do not deepen past 6 or cap launch_bounds.
__device__ inline void gather_tile(const u16* __restrict__ src,
                                   const int* __restrict__ rowptr,
                                   const u16* __restrict__ csr,
                                   int node, int m, int q, int wv,
                                   short (*AT)[16][64]) {
    int beg = rowptr[node], end = rowptr[node + 1];
    float2 ac[8];
#pragma unroll
    for (int i = 0; i < 8; i++) ac[i] = make_float2(0.f, 0.f);
    int j = beg;
    for (; j + 5 < end; j += 6) {
        int r0 = csr[j],     r1 = csr[j + 1], r2 = csr[j + 2];
        int r3 = csr[j + 3], r4 = csr[j + 4], r5 = csr[j + 5];
        const uint4* p0 = (const uint4*)(src + (size_t)r0 * 64 + q * 16);
        const uint4* p1 = (const uint4*)(src + (size_t)r1 * 64 + q * 16);
        const uint4* p2 = (const uint4*)(src + (size_t)r2 * 64 + q * 16);
        const uint4* p3 = (const uint4*)(src + (size_t)r3 * 64 + q * 16);
        const uint4* p4 = (const uint4*)(src + (size_t)r4 * 64 + q * 16);
        const uint4* p5 = (const uint4*)(src + (size_t)r5 * 64 + q * 16);
        uint4 v00 = p0[0], v01 = p0[1];
        uint4 v10 = p1[0], v11 = p1[1];
        uint4 v20 = p2[0], v21 = p2[1];
        uint4 v30 = p3[0], v31 = p3[1];
        uint4 v40 = p4[0], v41 = p4[1];
        uint4 v50 = p5[0], v51 = p5[1];
        accp(ac, v00); accp(ac + 4, v01);
        accp(ac, v10); accp(ac + 4, v11);
        accp(ac, v20); accp(ac + 4, v21);
        accp(ac, v30); accp(ac + 4, v31);
        accp(ac, v40); accp(ac + 4, v41);
        accp(ac, v50); accp(ac + 4, v51);
    }
    for (; j + 3 < end; j += 4) {
        int r0 = csr[j], r1 = csr[j + 1], r2 = csr[j + 2], r3 = csr[j + 3];
        const uint4* p0 = (const uint4*)(src + (size_t)r0 * 64 + q * 16);
        const uint4* p1 = (const uint4*)(src + (size_t)r1 * 64 + q * 16);
        const uint4* p2 = (const uint4*)(src + (size_t)r2 * 64 + q * 16);
        const uint4* p3 = (const uint4*)(src + (size_t)r3 * 64 + q * 16);
        uint4 v00 = p0[0], v01 = p0[1];
        uint4 v10 = p1[0], v11 = p1[1];
        uint4 v20 = p2[0], v21 = p2[1];
        uint4 v30 = p3[0], v31 = p3[1];
        accp(ac, v00); accp(ac + 4, v01);
        accp(ac, v10); accp(ac + 4, v11);
        accp(ac, v20); accp(ac + 4, v21);
        accp(ac, v30); accp(ac + 4, v31);
    }
    for (; j < end; j++) {
        int r = csr[j];
        const uint4* p = (const uint4*)(src + (size_t)r * 64 + q * 16);
        uint4 v0 = p[0], v1 = p[1];
        accp(ac, v0); accp(ac + 4, v1);
    }
    float inv = 1.0f / (float)(end - beg);   // deg > 0 always
    uint4 lo, hi;
    lo.x = pkbf(ac[0].x * inv, ac[0].y * inv);
    lo.y = pkbf(ac[1].x * inv, ac[1].y * inv);
    lo.z = pkbf(ac[2].x * inv, ac[2].y * inv);
    lo.w = pkbf(ac[3].x * inv, ac[3].y * inv);
    hi.x = pkbf(ac[4].x * inv, ac[4].y * inv);
    hi.y = pkbf(ac[5].x * inv, ac[5].y * inv);
    hi.z = pkbf(ac[6].x * inv, ac[6].y * inv);
    hi.w = pkbf(ac[7].x * inv, ac[7].y * inv);
    *(uint4*)&AT[wv][m][((2 * q) ^ (m & 7)) * 8]     = lo;
    *(uint4*)&AT[wv][m][((2 * q + 1) ^ (m & 7)) * 8] = hi;
}

// fused h-gather + edge_emb MFMA, degree-sorted tiles via perm.
__global__ __launch_bounds__(256) void k_edge_f(
        const u16* __restrict__ h, const int* __restrict__ rowptr,
        const u16* __restrict__ csr, const int* __restrict__ dmax,
        const float* __restrict__ We2, const int* __restrict__ perm,
        u16* __restrict__ ee) {
    __shared__ unsigned SB[2][4][64][4];   // 8KB
    __shared__ short AT[4][16][64];        // 8KB
    int t = threadIdx.x;
    for (int F = t; F < 512; F += 256) {
        int ks = F >> 8, tile = (F >> 6) & 3, ln = F & 63;
        int c = ln & 15, qq = ln >> 4;
        const float* W = We2 + (ks * 32 + qq * 8) * 64 + tile * 16 + c;
        unsigned d0 = pkbf(W[0],       W[64]);
        unsigned d1 = pkbf(W[2 * 64],  W[3 * 64]);
        unsigned d2 = pkbf(W[4 * 64],  W[5 * 64]);
        unsigned d3 = pkbf(W[6 * 64],  W[7 * 64]);
        int slot = ln ^ ((ln >> 3) & 7);
        SB[ks][tile][slot][0] = d0; SB[ks][tile][slot][1] = d1;
        SB[ks][tile][slot][2] = d2; SB[ks][tile][slot][3] = d3;
    }
    __syncthreads();
    int wv = t >> 6, lane = t & 63;
    int m = lane & 15, quad = lane >> 4;
    int slot = lane ^ ((lane >> 3) & 7);
    float idm = 1.0f / (float)dmax[0];
    for (int tb = blockIdx.x * 4 + wv; tb < NTILES; tb += gridDim.x * 4) {
        int base = tb * 16;
        int pn = perm[base + m];
        gather_tile(h, rowptr, csr, pn, m, quad, wv, AT);
        float dv = (float)(rowptr[pn + 1] - rowptr[pn]) * idm;
        int prw[4];
#pragma unroll
        for (int r = 0; r < 4; r++) prw[r] = perm[base + quad * 4 + r];
        f32x4 acc[4];
#pragma unroll
        for (int i = 0; i < 4; i++) acc[i] = (f32x4){0.f, 0.f, 0.f, 0.f};
#pragma unroll
        for (int ks = 0; ks < 2; ks++) {
            int gp = (ks * 4 + quad) ^ (m & 7);
            bf16x8 a = *(const bf16x8*)&AT[wv][m][gp * 8];
            if (ks == 1 && quad == 3) a[7] = bf1(dv);   // k=63 column
#pragma unroll
            for (int tile = 0; tile < 4; tile++) {
                bf16x8 b = *(const bf16x8*)&SB[ks][tile][slot][0];
                acc[tile] = __builtin_amdgcn_mfma_f32_16x16x32_bf16(a, b, acc[tile], 0, 0, 0);
            }
        }
#pragma unroll
        for (int tile = 0; tile < 4; tile++)
#pragma unroll
            for (int r = 0; r < 4; r++)
                ee[(size_t)prw[r] * 64 + tile * 16 + m] =
                    (u16)bf1(fmaxf(acc[tile][r], 0.f));
    }
}

// fused gather + MPNN layer, degree-sorted tiles via perm. XT: agg tile for
// GEMM1 then msg tile for GEMM2 (disjoint lifetimes, 40KB LDS total).
template <bool F32OUT>
__global__ __launch_bounds__(256) void k_flayer(
        const u16* __restrict__ cur, const u16* __restrict__ ee,
        const int* __restrict__ rowptr, const u16* __restrict__ csr,
        const float* __restrict__ Wm, const float* __restrict__ Wu,
        const int* __restrict__ perm, void* __restrict__ outp) {
    __shared__ unsigned SB[2][4][4][64][4];   // 32KB
    __shared__ short XT[4][16][64];           // 8KB
    int t = threadIdx.x;
    for (int F = t; F < 2048; F += 256) {
        int g = F >> 10, ks = (F >> 8) & 3, tile = (F >> 6) & 3, ln = F & 63;
        int c = ln & 15, qq = ln >> 4;
        const float* W = (g ? Wu : Wm) + (ks * 32 + qq * 8) * 64 + tile * 16 + c;
        unsigned d0 = pkbf(W[0],      W[64]);
        unsigned d1 = pkbf(W[2 * 64], W[3 * 64]);
        unsigned d2 = pkbf(W[4 * 64], W[5 * 64]);
        unsigned d3 = pkbf(W[6 * 64], W[7 * 64]);
        int slot = ln ^ ((ln >> 3) & 7);
        SB[g][ks][tile][slot][0] = d0; SB[g][ks][tile][slot][1] = d1;
        SB[g][ks][tile][slot][2] = d2; SB[g][ks][tile][slot][3] = d3;
    }
    __syncthreads();
    int wv = t >> 6, lane = t & 63;
    int m = lane & 15, quad = lane >> 4;
    int slot = lane ^ ((lane >> 3) & 7);
    for (int tb = blockIdx.x * 4 + wv; tb < NTILES; tb += gridDim.x * 4) {
        int base = tb * 16;
        int pn = perm[base + m];
        gather_tile(cur, rowptr, csr, pn, m, quad, wv, XT);
        const u16* erow = ee  + (size_t)pn * 64;
        const u16* crow = cur + (size_t)pn * 64;
        int prw[4];
#pragma unroll
        for (int r = 0; r < 4; r++) prw[r] = perm[base + quad * 4 + r];
        f32x4 acc[4];
#pragma unroll
        for (int i = 0; i < 4; i++) acc[i] = (f32x4){0.f, 0.f, 0.f, 0.f};
        // GEMM1: k 0..63 = agg (XT), 64..127 = ee (global)
#pragma unroll
        for (int ks = 0; ks < 4; ks++) {
            bf16x8 a;
            if (ks < 2) {
                int gp = (ks * 4 + quad) ^ (m & 7);
                a = *(const bf16x8*)&XT[wv][m][gp * 8];
            } else {
                a = *(const bf16x8*)(erow + (ks - 2) * 32 + quad * 8);
            }
#pragma unroll
            for (int tile = 0; tile < 4; tile++) {
                bf16x8 b = *(const bf16x8*)&SB[0][ks][tile][slot][0];
                acc[tile] = __builtin_amdgcn_mfma_f32_16x16x32_bf16(a, b, acc[tile], 0, 0, 0);
            }
        }
        // relu(msg) -> XT (reuse) in A-readable swizzled layout (wave-private)
#pragma unroll
        for (int tile = 0; tile < 4; tile++)
#pragma unroll
            for (int r = 0; r < 4; r++) {
                int node = quad * 4 + r;
                int f = tile * 16 + m;
                int sidx = (((f >> 3) ^ (node & 7)) << 3) | (f & 7);
                XT[wv][node][sidx] = bf1(fmaxf(acc[tile][r], 0.f));
            }
        // GEMM2: k 0..63 = cur (global bf16), 64..127 = msg (XT)
#pragma unroll
        for (int i = 0; i < 4; i++) acc[i] = (f32x4){0.f, 0.f, 0.f, 0.f};
#pragma unroll
        for (int ks = 0; ks < 4; ks++) {
            bf16x8 a;
            if (ks < 2) {
                a = *(const bf16x8*)(crow + ks * 32 + quad * 8);
            } else {
                int gp = ((ks - 2) * 4 + quad) ^ (m & 7);
                a = *(const bf16x8*)&XT[wv][m][gp << 3];
            }
#pragma unroll
            for (int tile = 0; tile < 4; tile++) {
                bf16x8 b = *(const bf16x8*)&SB[1][ks][tile][slot][0];
                acc[tile] = __builtin_amdgcn_mfma_f32_16x16x32_bf16(a, b, acc[tile], 0, 0, 0);
            }
        }
#pragma unroll
        for (int tile = 0; tile < 4; tile++)
#pragma unroll
            for (int r = 0; r < 4; r++) {
                float v = fmaxf(acc[tile][r], 0.f);
                size_t oi = (size_t)prw[r] * 64 + tile * 16 + m;
                if (F32OUT) ((float*)outp)[oi] = v;
                else        ((u16*)outp)[oi] = (u16)bf1(v);
            }
    }
}

// R21: atomic-free means partials (distinct addresses, no done-counter).
__global__ __launch_bounds__(256) void k_means2(const float* __restrict__ cur,
                                                float* __restrict__ pmeans) {
    int g = blockIdx.x / MCHUNK;
    int c = blockIdx.x % MCHUNK;
    int t = threadIdx.x, f = t & 63, q = t >> 6;
    int base = g * NPG + c * MROWS;
    float acc = 0.f;
    for (int n = base + q; n < base + MROWS; n += 4) acc += cur[(size_t)n * 64 + f];
    __shared__ float red[4][64];
    red[q][f] = acc;
    __syncthreads();
    if (q == 0)
        pmeans[(size_t)(g * MCHUNK + c) * 64 + f] =
            red[0][f] + red[1][f] + red[2][f] + red[3][f];
}

// r1[g] = sum_f relu((mean[g] @ Wp)[f]) * Wr[f]. One block.
__global__ __launch_bounds__(256) void k_pool2(
        const float* __restrict__ pmeans, const float* __restrict__ Wp,
        const float* __restrict__ Wr, float* __restrict__ r1) {
    __shared__ float sm[4][64];
    int wv = threadIdx.x >> 6, lane = threadIdx.x & 63;
    for (int g = wv; g < NG; g += 4) {
        float m = 0.f;
        const float* pm = pmeans + (size_t)g * MCHUNK * 64 + lane;
#pragma unroll
        for (int c = 0; c < MCHUNK; c++) m += pm[c * 64];
        sm[wv][lane] = m * (1.0f / NPG);
        float a2 = 0.f;
#pragma unroll 16
        for (int k = 0; k < 64; k++) a2 = fmaf(sm[wv][k], Wp[k * 64 + lane], a2);
        float v = fmaxf(a2, 0.f) * Wr[lane];
        for (int off = 32; off; off >>= 1) v += __shfl_xor(v, off, 64);
        if (lane == 0) r1[g] = v;
    }
}

// out[n] = b + r1[batch[n]] + dot(relu(cur[n]), Wr[64:])
__global__ void k_read2(const float* __restrict__ cur, const float* __restrict__ r1,
                        const int* __restrict__ batch, const float* __restrict__ Wr,
                        const float* __restrict__ br, float* __restrict__ out) {
    int idx = blockIdx.x * 256 + threadIdx.x;
    int node = idx >> 4;
    if (node >= N_NODES) return;
    int q = idx & 15;
    float4 c = *(const float4*)(cur + (size_t)node * 64 + q * 4);
    float4 w = *(const float4*)(Wr + 64 + q * 4);
    float v = fmaxf(c.x, 0.f) * w.x + fmaxf(c.y, 0.f) * w.y
            + fmaxf(c.z, 0.f) * w.z + fmaxf(c.w, 0.f) * w.w;
    v += __shfl_xor(v, 1, 64); v += __shfl_xor(v, 2, 64);
    v += __shfl_xor(v, 4, 64); v += __shfl_xor(v, 8, 64);
    if (q == 0) out[node] = v + r1[batch[node]] + br[0];
}

// ---------------------------------------------------------------------------
extern "C" void kernel_launch(void* const* d_in, const int* in_sizes, int n_in,
                              void* d_out, int out_size, void* d_ws, size_t ws_size,
                              hipStream_t stream) {
    const float* x    = (const float*)d_in[0];
    const float* Wi   = (const float*)d_in[1];
    const float* We1  = (const float*)d_in[2];
    const float* We2  = (const float*)d_in[3];
    const float* Wm   = (const float*)d_in[4];   // [3,128,64]
    const float* Wu   = (const float*)d_in[5];   // [3,128,64]
    const float* Wp   = (const float*)d_in[6];
    const float* Wr   = (const float*)d_in[7];
    const float* br   = (const float*)d_in[8];
    const int*   ei   = (const int*)d_in[9];     // [2,E]
    const int*   batch= (const int*)d_in[10];
    const int* row = ei;
    const int* col = ei + N_EDGES;
    float* out = (float*)d_out;

    char* w = (char*)d_ws;
    size_t off = 0;
    auto carve = [&](size_t bytes) -> void* {
        void* p = (void*)(w + off);
        off += (bytes + 255) & ~(size_t)255;
        return p;
    };
    // zero-init region (one memset: dmax + hist + binBump + bktCnt)
    int*   dmax     = (int*)carve(256);
    int*   hist     = (int*)carve(256 * 4);
    int*   binBump  = (int*)carve(256 * 4);
    int*   bktCnt   = (int*)carve(256 * 4);
    size_t zero_span = off;
    unsigned* bktData = (unsigned*)carve((size_t)NBKT * BKT_CAP * 4);  // 4.8MB
    int*   deg      = (int*)carve((size_t)N_NODES * 4);   // dense, fully written
    int*   rowptr   = (int*)carve((size_t)(N_NODES + 1) * 4);
    u16*   csr      = (u16*)carve((size_t)N_EDGES * 2);
    int*   perm     = (int*)carve((size_t)N_NODES * 4);
    float* pmeans   = (float*)carve((size_t)NG * MCHUNK * 64 * 4);
    u16*   bufA     = (u16*)carve((size_t)N_NODES * 64 * 2);
    u16*   bufB     = (u16*)carve((size_t)N_NODES * 64 * 2);
    u16*   ee       = (u16*)carve((size_t)N_NODES * 64 * 2);
    float* curF     = (float*)carve((size_t)N_NODES * 64 * 4);
    float* r1       = (float*)carve((size_t)NG * 4);

    hipMemsetAsync(d_ws, 0, zero_span, stream);

    // R25 bucket-radix CSR build (atomic-light) fused with node init
    k_bucket_init<<<P1_BLKS + INIT_BLKS, 256, 0, stream>>>(row, col, bktCnt, bktData,
                                                           x, Wi, We1, bufA, bufB);
    k_bsort   <<<NBKT, 256, 0, stream>>>(bktData, bktCnt, deg, rowptr, csr);
    // dmax + degree histogram, then descending-degree counting-sort perm
    k_blocksum<<<SCAN_NBLK, 256, 0, stream>>>(deg, dmax, hist);
    k_permsort<<<SCAN_NBLK, 256, 0, stream>>>(deg, hist, binBump, perm);

    // fused h-gather + edge embedding (bufB = h)
    k_edge_f<<<GATHER_BLKS, 256, 0, stream>>>(bufB, rowptr, csr, dmax, We2, perm, ee);

    // fused gather+layer x3: A->B, B->A, A->curF(fp32)
    k_flayer<false><<<GATHER_BLKS, 256, 0, stream>>>(bufA, ee, rowptr, csr,
                                                     Wm, Wu, perm, bufB);
    k_flayer<false><<<GATHER_BLKS, 256, 0, stream>>>(bufB, ee, rowptr, csr,
                                                     Wm + 128 * 64, Wu + 128 * 64,
                                                     perm, bufA);
    k_flayer<true> <<<GATHER_BLKS, 256, 0, stream>>>(bufA, ee, rowptr, csr,
                                                     Wm + 2 * 128 * 64, Wu + 2 * 128 * 64,
                                                     perm, curF);

    // atomic-free means partials -> tiny pool kernel
    k_means2<<<NG * MCHUNK, 256, 0, stream>>>(curF, pmeans);
    k_pool2 <<<1, 256, 0, stream>>>(pmeans, Wp, Wr, r1);
    k_read2<<<(N_NODES * 16 + 255) / 256, 256, 0, stream>>>(curF, r1, batch, Wr, br, out);
}